// Round 1
// baseline (1037.305 us; speedup 1.0000x reference)
//
#include <hip/hip_runtime.h>
#include <math.h>

#define B_   1024
#define M_   10
#define M1_  11
#define DIM_ 128
#define NW_  201   // real weight rows in entity_gcn_weight; Rt >= 201 -> zero matrix

// ---------------------------------------------------------------------------
// R-GCN: one block per (b, j); 128 threads, thread e computes out[b][j][e].
// out[b,j,e] = relu( sum_{k<=nn} D[b,j,k] * sum_d H[b,j,d] * W[R[b,j,k]][d][e] )
// rows with j > nn are zero.
// ---------------------------------------------------------------------------
__global__ __launch_bounds__(128)
void rgcn_kernel(const float* __restrict__ ent_emb,
                 const float* __restrict__ ent_ctx,
                 const float* __restrict__ W,
                 const int* __restrict__ center,
                 const int* __restrict__ adj,   // B*M
                 const int* __restrict__ Rt,    // B*M1*M1
                 const int* __restrict__ nn,    // B
                 const float* __restrict__ Dm,  // B*M1*M1
                 float* __restrict__ vout)      // B*M1*DIM
{
    __shared__ float sH[DIM_];
    const int bx = blockIdx.x;
    const int b = bx / M1_;
    const int j = bx % M1_;
    const int e = threadIdx.x;
    float* outp = vout + (size_t)bx * DIM_;
    const int n = nn[b];
    if (j > n) { outp[e] = 0.f; return; }

    float h;
    if (j == 0) h = ent_emb[(size_t)center[b] * DIM_ + e];
    else        h = ent_ctx[(size_t)adj[b * M_ + (j - 1)] * DIM_ + e];
    sH[e] = h;
    __syncthreads();

    float acc = 0.f;
    const int base = (b * M1_ + j) * M1_;
    for (int k = 0; k <= n; ++k) {
        const int r = Rt[base + k];
        if (r >= NW_) continue;            // padded / zero-weight relation type
        const float dk = Dm[base + k];
        const float* Wp = W + (size_t)r * (DIM_ * DIM_) + e;
        float y = 0.f;
        #pragma unroll 16
        for (int d = 0; d < DIM_; ++d) y += sH[d] * Wp[(size_t)d * DIM_];
        acc += dk * y;
    }
    outp[e] = fmaxf(acc, 0.f);
}

// ---------------------------------------------------------------------------
// Relation GCN: one block per b. out[b,i,:] = relu((A[b] @ H[b]) @ Wr)
// H[b,0] = rel_emb[center], H[b,j] = rel_ctx[adj[b,j-1,0]] + rel_ctx[adj[b,j-1,1]]
// ---------------------------------------------------------------------------
__global__ __launch_bounds__(128)
void gcnrel_kernel(const float* __restrict__ rel_emb,
                   const float* __restrict__ rel_ctx,
                   const float* __restrict__ Wr,
                   const int* __restrict__ center,
                   const int* __restrict__ adj2,   // B*M*2
                   const float* __restrict__ A,    // B*121
                   float* __restrict__ vout)       // B*M1*DIM
{
    __shared__ float sH[M1_][DIM_];
    __shared__ float sAH[M1_][DIM_];
    __shared__ float sA[M1_ * M1_];
    const int b = blockIdx.x;
    const int e = threadIdx.x;

    sH[0][e] = rel_emb[(size_t)center[b] * DIM_ + e];
    #pragma unroll
    for (int j = 1; j < M1_; ++j) {
        const int a0 = adj2[((b * M_) + (j - 1)) * 2 + 0];
        const int a1 = adj2[((b * M_) + (j - 1)) * 2 + 1];
        sH[j][e] = rel_ctx[(size_t)a0 * DIM_ + e] + rel_ctx[(size_t)a1 * DIM_ + e];
    }
    if (e < M1_ * M1_) sA[e] = A[b * (M1_ * M1_) + e];
    __syncthreads();

    #pragma unroll
    for (int i = 0; i < M1_; ++i) {
        float s = 0.f;
        #pragma unroll
        for (int jj = 0; jj < M1_; ++jj) s += sA[i * M1_ + jj] * sH[jj][e];
        sAH[i][e] = s;
    }
    __syncthreads();

    float acc[M1_];
    #pragma unroll
    for (int i = 0; i < M1_; ++i) acc[i] = 0.f;
    for (int d = 0; d < DIM_; ++d) {
        const float w = Wr[d * DIM_ + e];
        #pragma unroll
        for (int i = 0; i < M1_; ++i) acc[i] += sAH[i][d] * w;
    }
    float* outp = vout + (size_t)b * (M1_ * DIM_);
    #pragma unroll
    for (int i = 0; i < M1_; ++i) outp[i * DIM_ + e] = fmaxf(acc[i], 0.f);
}

// ---------------------------------------------------------------------------
// Final: subgraph attention + gating + L2 score. One block per b, 128 threads.
// ---------------------------------------------------------------------------
__device__ __forceinline__ float reduce128(float x, float* red) {
    #pragma unroll
    for (int o = 32; o > 0; o >>= 1) x += __shfl_down(x, o, 64);
    __syncthreads();
    if ((threadIdx.x & 63) == 0) red[threadIdx.x >> 6] = x;
    __syncthreads();
    return red[0] + red[1];
}

__device__ float subgraph_sg(const float* __restrict__ vmat, float o, float ve,
                             int e, float* red) {
    float vm[M1_], sc[M1_];
    #pragma unroll
    for (int j = 0; j < M1_; ++j) vm[j] = vmat[j * DIM_ + e];
    #pragma unroll
    for (int j = 0; j < M1_; ++j)
        sc[j] = reduce128(fmaxf(vm[j] * o, 0.f) * ve, red);
    float mx = sc[0];
    #pragma unroll
    for (int j = 1; j < M1_; ++j) mx = fmaxf(mx, sc[j]);
    float s = 0.f;
    float ex[M1_];
    #pragma unroll
    for (int j = 0; j < M1_; ++j) { ex[j] = expf(sc[j] - mx); s += ex[j]; }
    const float inv = 1.f / s;
    float sg = 0.f;
    #pragma unroll
    for (int j = 0; j < M1_; ++j) sg += ex[j] * inv * vm[j];
    return sg;
}

__global__ __launch_bounds__(128)
void final_kernel(const float* __restrict__ ent_emb,
                  const float* __restrict__ rel_emb,
                  const int* __restrict__ pos_h, const int* __restrict__ pos_r,
                  const int* __restrict__ pos_t,
                  const int* __restrict__ neg_h, const int* __restrict__ neg_r,
                  const int* __restrict__ neg_t,
                  const float* __restrict__ gate_e, const float* __restrict__ gate_r,
                  const float* __restrict__ v_ent, const float* __restrict__ v_rel,
                  const float* __restrict__ vent,   // 4*B*M1*DIM
                  const float* __restrict__ vrel,   // 2*B*M1*DIM
                  float* __restrict__ out)          // 2*B
{
    __shared__ float red[2];
    const int b = blockIdx.x;
    const int e = threadIdx.x;
    const float p_h = ent_emb[(size_t)pos_h[b] * DIM_ + e];
    const float p_t = ent_emb[(size_t)pos_t[b] * DIM_ + e];
    const float p_r = rel_emb[(size_t)pos_r[b] * DIM_ + e];
    const float n_h = ent_emb[(size_t)neg_h[b] * DIM_ + e];
    const float n_t = ent_emb[(size_t)neg_t[b] * DIM_ + e];
    const float n_r = rel_emb[(size_t)neg_r[b] * DIM_ + e];
    const float ve = v_ent[e], vr = v_rel[e];
    const size_t cs = (size_t)B_ * M1_ * DIM_;
    const size_t bo = (size_t)b * M1_ * DIM_;

    const float ph_sg = subgraph_sg(vent + 0 * cs + bo, p_h, ve, e, red);
    const float pt_sg = subgraph_sg(vent + 1 * cs + bo, p_t, ve, e, red);
    const float nh_sg = subgraph_sg(vent + 2 * cs + bo, n_h, ve, e, red);
    const float nt_sg = subgraph_sg(vent + 3 * cs + bo, n_t, ve, e, red);
    const float pr_sg = subgraph_sg(vrel + 0 * cs + bo, p_r, vr, e, red);
    const float nr_sg = subgraph_sg(vrel + 1 * cs + bo, n_r, vr, e, red);

    const float ge = 1.f / (1.f + expf(-gate_e[e]));
    const float gr = 1.f / (1.f + expf(-gate_r[e]));
    const float ph_o = ge * p_h + (1.f - ge) * ph_sg;
    const float pt_o = ge * p_t + (1.f - ge) * pt_sg;
    const float nh_o = ge * n_h + (1.f - ge) * nh_sg;
    const float nt_o = ge * n_t + (1.f - ge) * nt_sg;
    const float pr_o = gr * p_r + (1.f - gr) * pr_sg;
    const float nr_o = gr * n_r + (1.f - gr) * nr_sg;

    const float pv = ph_o + pr_o - pt_o;
    const float ps2 = reduce128(pv * pv, red);
    const float nv = nh_o + nr_o - nt_o;
    const float ns2 = reduce128(nv * nv, red);
    if (e == 0) { out[b] = sqrtf(ps2); out[B_ + b] = sqrtf(ns2); }
}

extern "C" void kernel_launch(void* const* d_in, const int* in_sizes, int n_in,
                              void* d_out, int out_size, void* d_ws, size_t ws_size,
                              hipStream_t stream)
{
    const float* entity_emb   = (const float*)d_in[0];
    const float* relation_emb = (const float*)d_in[1];
    const float* entity_ctx   = (const float*)d_in[2];
    const float* relation_ctx = (const float*)d_in[3];
    const float* egw          = (const float*)d_in[4];
    const float* rgw          = (const float*)d_in[5];
    const float* gate_e       = (const float*)d_in[6];
    const float* gate_r       = (const float*)d_in[7];
    const float* v_ent        = (const float*)d_in[8];
    const float* v_rel        = (const float*)d_in[9];
    const int* pos_h = (const int*)d_in[10];
    const int* pos_r = (const int*)d_in[11];
    const int* pos_t = (const int*)d_in[12];
    const int* neg_h = (const int*)d_in[13];
    const int* neg_r = (const int*)d_in[14];
    const int* neg_t = (const int*)d_in[15];
    const int* ph_adj = (const int*)d_in[16];
    const int* pt_adj = (const int*)d_in[17];
    const int* nh_adj = (const int*)d_in[18];
    const int* nt_adj = (const int*)d_in[19];
    const int* pr_adj = (const int*)d_in[20];
    const int* nr_adj = (const int*)d_in[21];
    const int* ph_R = (const int*)d_in[22];
    const int* pt_R = (const int*)d_in[23];
    const int* nh_R = (const int*)d_in[24];
    const int* nt_R = (const int*)d_in[25];
    const int* ph_nn = (const int*)d_in[26];
    const int* pt_nn = (const int*)d_in[27];
    const int* nh_nn = (const int*)d_in[28];
    const int* nt_nn = (const int*)d_in[29];
    const float* ph_D = (const float*)d_in[30];
    const float* pt_D = (const float*)d_in[31];
    const float* nh_D = (const float*)d_in[32];
    const float* nt_D = (const float*)d_in[33];
    const float* pr_A = (const float*)d_in[34];
    const float* nr_A = (const float*)d_in[35];

    float* vent = (float*)d_ws;
    const size_t cs = (size_t)B_ * M1_ * DIM_;
    float* vrel = vent + 4 * cs;

    dim3 blk(128);
    dim3 gE(B_ * M1_);
    rgcn_kernel<<<gE, blk, 0, stream>>>(entity_emb, entity_ctx, egw, pos_h, ph_adj, ph_R, ph_nn, ph_D, vent + 0 * cs);
    rgcn_kernel<<<gE, blk, 0, stream>>>(entity_emb, entity_ctx, egw, pos_t, pt_adj, pt_R, pt_nn, pt_D, vent + 1 * cs);
    rgcn_kernel<<<gE, blk, 0, stream>>>(entity_emb, entity_ctx, egw, neg_h, nh_adj, nh_R, nh_nn, nh_D, vent + 2 * cs);
    rgcn_kernel<<<gE, blk, 0, stream>>>(entity_emb, entity_ctx, egw, neg_t, nt_adj, nt_R, nt_nn, nt_D, vent + 3 * cs);
    gcnrel_kernel<<<dim3(B_), blk, 0, stream>>>(relation_emb, relation_ctx, rgw, pos_r, pr_adj, pr_A, vrel + 0 * cs);
    gcnrel_kernel<<<dim3(B_), blk, 0, stream>>>(relation_emb, relation_ctx, rgw, neg_r, nr_adj, nr_A, vrel + 1 * cs);
    final_kernel<<<dim3(B_), blk, 0, stream>>>(entity_emb, relation_emb,
        pos_h, pos_r, pos_t, neg_h, neg_r, neg_t,
        gate_e, gate_r, v_ent, v_rel, vent, vrel, (float*)d_out);
}

// Round 2
// 612.384 us; speedup vs baseline: 1.6939x; 1.6939x over previous
//
#include <hip/hip_runtime.h>
#include <math.h>

#define B_   1024
#define M_   10
#define M1_  11
#define DIM_ 128
#define NW_  201                    // real weight rows; r >= 201 -> zero matrix
#define NQUAD_ (4*B_*M1_*M1_)       // 495616 (case,b,j,k) quadruples
#define IPB_  32                    // items per GEMM block
#define MAXCH_ ((NQUAD_ + IPB_ - 1)/IPB_)
#define MAXBLK_ (NW_ + MAXCH_)      // upper bound on GEMM blocks

struct GatherPtrs {
    const int* center[4];
    const int* adj[4];
    const int* nn[4];
    const int* Rt[4];
    const float* Dm[4];
};

// ---------------------------------------------------------------------------
// Pass 1: histogram of valid items per relation type
// ---------------------------------------------------------------------------
__global__ __launch_bounds__(256)
void hist_kernel(GatherPtrs gp, int* __restrict__ hist)
{
    const int idx = blockIdx.x * 256 + threadIdx.x;
    const int c = idx / (B_ * M1_ * M1_);
    const int rem = idx % (B_ * M1_ * M1_);
    const int b = rem / (M1_ * M1_);
    const int jk = rem % (M1_ * M1_);
    const int j = jk / M1_, k = jk % M1_;
    const int n = gp.nn[c][b];
    if (j <= n && k <= n) {
        const int r = gp.Rt[c][rem];
        if (r < NW_) atomicAdd(&hist[r], 1);
    }
}

// ---------------------------------------------------------------------------
// Pass 2: exclusive prefix sums (items and chunk-blocks) — single block
// ---------------------------------------------------------------------------
__global__ __launch_bounds__(256)
void scan_kernel(const int* __restrict__ hist, int* __restrict__ itemOff,
                 int* __restrict__ bstart)
{
    __shared__ int h[NW_];
    __shared__ int io[NW_ + 1];
    __shared__ int bs[NW_ + 1];
    const int t = threadIdx.x;
    if (t < NW_) h[t] = hist[t];
    __syncthreads();
    if (t == 0) {
        int accI = 0, accB = 0;
        for (int i = 0; i < NW_; ++i) {
            io[i] = accI; bs[i] = accB;
            accI += h[i]; accB += (h[i] + IPB_ - 1) / IPB_;
        }
        io[NW_] = accI; bs[NW_] = accB;
    }
    __syncthreads();
    if (t <= NW_) { itemOff[t] = io[t]; bstart[t] = bs[t]; }
}

// ---------------------------------------------------------------------------
// Pass 3: scatter packed items into t-sorted order
// ---------------------------------------------------------------------------
__global__ __launch_bounds__(256)
void scatter_kernel(GatherPtrs gp, const int* __restrict__ itemOff,
                    int* __restrict__ cursor, int* __restrict__ items)
{
    const int idx = blockIdx.x * 256 + threadIdx.x;
    const int c = idx / (B_ * M1_ * M1_);
    const int rem = idx % (B_ * M1_ * M1_);
    const int b = rem / (M1_ * M1_);
    const int jk = rem % (M1_ * M1_);
    const int j = jk / M1_, k = jk % M1_;
    const int n = gp.nn[c][b];
    if (j <= n && k <= n) {
        const int r = gp.Rt[c][rem];
        if (r < NW_) {
            const int slot = itemOff[r] + atomicAdd(&cursor[r], 1);
            items[slot] = (c << 18) | (b << 8) | (j << 4) | k;
        }
    }
}

// ---------------------------------------------------------------------------
// Pass 4: grouped GEMM. One block per (t, chunk of 32 items).
// Stages W[t] (64 KB) in LDS once; each item contributes D * (H @ W[t])
// accumulated into vent via f32 atomics.
// Thread layout: q = tid&31 -> e-quad [4q..4q+3]; g = tid>>5 -> items [4g..4g+3].
// ---------------------------------------------------------------------------
__global__ __launch_bounds__(256, 1)
void rgcn_gemm_kernel(GatherPtrs gp,
                      const float* __restrict__ ent_emb,
                      const float* __restrict__ ent_ctx,
                      const float* __restrict__ W,
                      const int* __restrict__ items,
                      const int* __restrict__ itemOff,
                      const int* __restrict__ bstart,
                      float* __restrict__ vent)
{
    __shared__ float4 sWv[DIM_ * DIM_ / 4];   // 64 KB, row-major [d][e]
    __shared__ float4 sHv[IPB_ * DIM_ / 4];   // 16 KB, [item][d], pre-scaled by D

    const int bid = blockIdx.x;
    if (bid >= bstart[NW_]) return;
    // binary search: largest t with bstart[t] <= bid
    int lo = 0, hi = NW_;
    while (lo + 1 < hi) { const int mid = (lo + hi) >> 1; if (bstart[mid] <= bid) lo = mid; else hi = mid; }
    const int t = lo;
    const int istart = itemOff[t] + (bid - bstart[t]) * IPB_;
    const int nItems = min(IPB_, itemOff[t + 1] - istart);
    const int tid = threadIdx.x;

    // stage W[t] (coalesced, linear)
    const float4* Wg = (const float4*)(W + (size_t)t * DIM_ * DIM_);
    #pragma unroll
    for (int i = 0; i < 16; ++i) sWv[i * 256 + tid] = Wg[i * 256 + tid];

    // stage H rows scaled by D; 8 threads per item, 16 floats each
    {
        const int it = tid >> 3, part = tid & 7;
        float4* dst = sHv + it * (DIM_ / 4);
        if (it < nItems) {
            const int p = items[istart + it];
            const int c = p >> 18, b = (p >> 8) & 1023, j = (p >> 4) & 15, k = p & 15;
            const float* src = (j == 0)
                ? ent_emb + (size_t)gp.center[c][b] * DIM_
                : ent_ctx + (size_t)gp.adj[c][b * M_ + (j - 1)] * DIM_;
            const float d = gp.Dm[c][(b * M1_ + j) * M1_ + k];
            const float4* s4 = (const float4*)src;
            #pragma unroll
            for (int s = 0; s < 4; ++s) {
                float4 v = s4[part * 4 + s];
                v.x *= d; v.y *= d; v.z *= d; v.w *= d;
                dst[part * 4 + s] = v;
            }
        } else {
            const float4 z = {0.f, 0.f, 0.f, 0.f};
            #pragma unroll
            for (int s = 0; s < 4; ++s) dst[part * 4 + s] = z;
        }
    }
    __syncthreads();

    const int q = tid & 31, g = tid >> 5;
    float acc[4][4] = {};
    #pragma unroll 2
    for (int d0 = 0; d0 < DIM_; d0 += 4) {
        const float4 w0 = sWv[(d0 + 0) * 32 + q];
        const float4 w1 = sWv[(d0 + 1) * 32 + q];
        const float4 w2 = sWv[(d0 + 2) * 32 + q];
        const float4 w3 = sWv[(d0 + 3) * 32 + q];
        #pragma unroll
        for (int m = 0; m < 4; ++m) {
            const float4 h = sHv[(4 * g + m) * 32 + (d0 >> 2)];
            acc[m][0] += h.x * w0.x + h.y * w1.x + h.z * w2.x + h.w * w3.x;
            acc[m][1] += h.x * w0.y + h.y * w1.y + h.z * w2.y + h.w * w3.y;
            acc[m][2] += h.x * w0.z + h.y * w1.z + h.z * w2.z + h.w * w3.z;
            acc[m][3] += h.x * w0.w + h.y * w1.w + h.z * w2.w + h.w * w3.w;
        }
    }

    #pragma unroll
    for (int m = 0; m < 4; ++m) {
        const int it = 4 * g + m;
        if (it < nItems) {
            const int p = items[istart + it];
            const int c = p >> 18, b = (p >> 8) & 1023, j = (p >> 4) & 15;
            float* dstp = vent + (((size_t)(c * B_ + b)) * M1_ + j) * DIM_ + 4 * q;
            unsafeAtomicAdd(dstp + 0, acc[m][0]);
            unsafeAtomicAdd(dstp + 1, acc[m][1]);
            unsafeAtomicAdd(dstp + 2, acc[m][2]);
            unsafeAtomicAdd(dstp + 3, acc[m][3]);
        }
    }
}

// ---------------------------------------------------------------------------
// Relation GCN (unchanged from round 0)
// ---------------------------------------------------------------------------
__global__ __launch_bounds__(128)
void gcnrel_kernel(const float* __restrict__ rel_emb,
                   const float* __restrict__ rel_ctx,
                   const float* __restrict__ Wr,
                   const int* __restrict__ center,
                   const int* __restrict__ adj2,
                   const float* __restrict__ A,
                   float* __restrict__ vout)
{
    __shared__ float sH[M1_][DIM_];
    __shared__ float sAH[M1_][DIM_];
    __shared__ float sA[M1_ * M1_];
    const int b = blockIdx.x;
    const int e = threadIdx.x;

    sH[0][e] = rel_emb[(size_t)center[b] * DIM_ + e];
    #pragma unroll
    for (int j = 1; j < M1_; ++j) {
        const int a0 = adj2[((b * M_) + (j - 1)) * 2 + 0];
        const int a1 = adj2[((b * M_) + (j - 1)) * 2 + 1];
        sH[j][e] = rel_ctx[(size_t)a0 * DIM_ + e] + rel_ctx[(size_t)a1 * DIM_ + e];
    }
    if (e < M1_ * M1_) sA[e] = A[b * (M1_ * M1_) + e];
    __syncthreads();

    #pragma unroll
    for (int i = 0; i < M1_; ++i) {
        float s = 0.f;
        #pragma unroll
        for (int jj = 0; jj < M1_; ++jj) s += sA[i * M1_ + jj] * sH[jj][e];
        sAH[i][e] = s;
    }
    __syncthreads();

    float acc[M1_];
    #pragma unroll
    for (int i = 0; i < M1_; ++i) acc[i] = 0.f;
    for (int d = 0; d < DIM_; ++d) {
        const float w = Wr[d * DIM_ + e];
        #pragma unroll
        for (int i = 0; i < M1_; ++i) acc[i] += sAH[i][d] * w;
    }
    float* outp = vout + (size_t)b * (M1_ * DIM_);
    #pragma unroll
    for (int i = 0; i < M1_; ++i) outp[i * DIM_ + e] = fmaxf(acc[i], 0.f);
}

// ---------------------------------------------------------------------------
// Final: subgraph attention + gating + L2 score
// ---------------------------------------------------------------------------
__device__ __forceinline__ float reduce128(float x, float* red) {
    #pragma unroll
    for (int o = 32; o > 0; o >>= 1) x += __shfl_down(x, o, 64);
    __syncthreads();
    if ((threadIdx.x & 63) == 0) red[threadIdx.x >> 6] = x;
    __syncthreads();
    return red[0] + red[1];
}

__device__ float subgraph_from_vm(const float* vm, float o, float ve, float* red) {
    float sc[M1_];
    #pragma unroll
    for (int j = 0; j < M1_; ++j)
        sc[j] = reduce128(fmaxf(vm[j] * o, 0.f) * ve, red);
    float mx = sc[0];
    #pragma unroll
    for (int j = 1; j < M1_; ++j) mx = fmaxf(mx, sc[j]);
    float s = 0.f;
    float ex[M1_];
    #pragma unroll
    for (int j = 0; j < M1_; ++j) { ex[j] = expf(sc[j] - mx); s += ex[j]; }
    const float inv = 1.f / s;
    float sg = 0.f;
    #pragma unroll
    for (int j = 0; j < M1_; ++j) sg += ex[j] * inv * vm[j];
    return sg;
}

__device__ float subgraph_ent(const float* __restrict__ vmat, int n, float o,
                              float ve, int e, float* red) {
    float vm[M1_];
    #pragma unroll
    for (int j = 0; j < M1_; ++j) {
        const float raw = vmat[j * DIM_ + e];
        vm[j] = (j <= n) ? fmaxf(raw, 0.f) : 0.f;
    }
    return subgraph_from_vm(vm, o, ve, red);
}

__device__ float subgraph_rel(const float* __restrict__ vmat, float o,
                              float ve, int e, float* red) {
    float vm[M1_];
    #pragma unroll
    for (int j = 0; j < M1_; ++j) vm[j] = vmat[j * DIM_ + e];
    return subgraph_from_vm(vm, o, ve, red);
}

__global__ __launch_bounds__(128)
void final_kernel(const float* __restrict__ ent_emb,
                  const float* __restrict__ rel_emb,
                  const int* __restrict__ pos_h, const int* __restrict__ pos_r,
                  const int* __restrict__ pos_t,
                  const int* __restrict__ neg_h, const int* __restrict__ neg_r,
                  const int* __restrict__ neg_t,
                  const int* __restrict__ ph_nn, const int* __restrict__ pt_nn,
                  const int* __restrict__ nh_nn, const int* __restrict__ nt_nn,
                  const float* __restrict__ gate_e, const float* __restrict__ gate_r,
                  const float* __restrict__ v_ent, const float* __restrict__ v_rel,
                  const float* __restrict__ vent,
                  const float* __restrict__ vrel,
                  float* __restrict__ out)
{
    __shared__ float red[2];
    const int b = blockIdx.x;
    const int e = threadIdx.x;
    const float p_h = ent_emb[(size_t)pos_h[b] * DIM_ + e];
    const float p_t = ent_emb[(size_t)pos_t[b] * DIM_ + e];
    const float p_r = rel_emb[(size_t)pos_r[b] * DIM_ + e];
    const float n_h = ent_emb[(size_t)neg_h[b] * DIM_ + e];
    const float n_t = ent_emb[(size_t)neg_t[b] * DIM_ + e];
    const float n_r = rel_emb[(size_t)neg_r[b] * DIM_ + e];
    const float ve = v_ent[e], vr = v_rel[e];
    const size_t cs = (size_t)B_ * M1_ * DIM_;
    const size_t bo = (size_t)b * M1_ * DIM_;

    const float ph_sg = subgraph_ent(vent + 0 * cs + bo, ph_nn[b], p_h, ve, e, red);
    const float pt_sg = subgraph_ent(vent + 1 * cs + bo, pt_nn[b], p_t, ve, e, red);
    const float nh_sg = subgraph_ent(vent + 2 * cs + bo, nh_nn[b], n_h, ve, e, red);
    const float nt_sg = subgraph_ent(vent + 3 * cs + bo, nt_nn[b], n_t, ve, e, red);
    const float pr_sg = subgraph_rel(vrel + 0 * cs + bo, p_r, vr, e, red);
    const float nr_sg = subgraph_rel(vrel + 1 * cs + bo, n_r, vr, e, red);

    const float ge = 1.f / (1.f + expf(-gate_e[e]));
    const float gr = 1.f / (1.f + expf(-gate_r[e]));
    const float ph_o = ge * p_h + (1.f - ge) * ph_sg;
    const float pt_o = ge * p_t + (1.f - ge) * pt_sg;
    const float nh_o = ge * n_h + (1.f - ge) * nh_sg;
    const float nt_o = ge * n_t + (1.f - ge) * nt_sg;
    const float pr_o = gr * p_r + (1.f - gr) * pr_sg;
    const float nr_o = gr * n_r + (1.f - gr) * nr_sg;

    const float pv = ph_o + pr_o - pt_o;
    const float ps2 = reduce128(pv * pv, red);
    const float nv = nh_o + nr_o - nt_o;
    const float ns2 = reduce128(nv * nv, red);
    if (e == 0) { out[b] = sqrtf(ps2); out[B_ + b] = sqrtf(ns2); }
}

extern "C" void kernel_launch(void* const* d_in, const int* in_sizes, int n_in,
                              void* d_out, int out_size, void* d_ws, size_t ws_size,
                              hipStream_t stream)
{
    const float* entity_emb   = (const float*)d_in[0];
    const float* relation_emb = (const float*)d_in[1];
    const float* entity_ctx   = (const float*)d_in[2];
    const float* relation_ctx = (const float*)d_in[3];
    const float* egw          = (const float*)d_in[4];
    const float* rgw          = (const float*)d_in[5];
    const float* gate_e       = (const float*)d_in[6];
    const float* gate_r       = (const float*)d_in[7];
    const float* v_ent        = (const float*)d_in[8];
    const float* v_rel        = (const float*)d_in[9];
    const int* pos_h = (const int*)d_in[10];
    const int* pos_r = (const int*)d_in[11];
    const int* pos_t = (const int*)d_in[12];
    const int* neg_h = (const int*)d_in[13];
    const int* neg_r = (const int*)d_in[14];
    const int* neg_t = (const int*)d_in[15];
    const int* ph_adj = (const int*)d_in[16];
    const int* pt_adj = (const int*)d_in[17];
    const int* nh_adj = (const int*)d_in[18];
    const int* nt_adj = (const int*)d_in[19];
    const int* pr_adj = (const int*)d_in[20];
    const int* nr_adj = (const int*)d_in[21];
    const int* ph_R = (const int*)d_in[22];
    const int* pt_R = (const int*)d_in[23];
    const int* nh_R = (const int*)d_in[24];
    const int* nt_R = (const int*)d_in[25];
    const int* ph_nn = (const int*)d_in[26];
    const int* pt_nn = (const int*)d_in[27];
    const int* nh_nn = (const int*)d_in[28];
    const int* nt_nn = (const int*)d_in[29];
    const float* ph_D = (const float*)d_in[30];
    const float* pt_D = (const float*)d_in[31];
    const float* nh_D = (const float*)d_in[32];
    const float* nt_D = (const float*)d_in[33];
    const float* pr_A = (const float*)d_in[34];
    const float* nr_A = (const float*)d_in[35];

    // workspace layout (fits in the 34.6 MB footprint proven in round 0):
    //   [0, 23.07 MB)          vent  (f32 atomic accumulators, zeroed per call)
    //   [23.07, 34.6 MB)       vrel  (written by gcnrel AFTER items/meta consumed)
    //     alias [23.07 +0, +1.98 MB)  items (t-sorted packed work list)
    //     alias [23.07 +8 MB, +4 KB)  meta: hist | itemOff | bstart | cursor
    char* wsb = (char*)d_ws;
    float* vent = (float*)wsb;
    const size_t ventBytes = (size_t)4 * B_ * M1_ * DIM_ * sizeof(float);  // 23,068,672
    float* vrel = (float*)(wsb + ventBytes);
    int* items = (int*)(wsb + ventBytes);
    int* meta  = (int*)(wsb + ventBytes + (8u << 20));
    int* hist    = meta;
    int* itemOff = meta + 256;
    int* bstart  = meta + 512;
    int* cursor  = meta + 768;

    GatherPtrs gp;
    gp.center[0] = pos_h; gp.center[1] = pos_t; gp.center[2] = neg_h; gp.center[3] = neg_t;
    gp.adj[0] = ph_adj; gp.adj[1] = pt_adj; gp.adj[2] = nh_adj; gp.adj[3] = nt_adj;
    gp.nn[0] = ph_nn; gp.nn[1] = pt_nn; gp.nn[2] = nh_nn; gp.nn[3] = nt_nn;
    gp.Rt[0] = ph_R; gp.Rt[1] = pt_R; gp.Rt[2] = nh_R; gp.Rt[3] = nt_R;
    gp.Dm[0] = ph_D; gp.Dm[1] = pt_D; gp.Dm[2] = nh_D; gp.Dm[3] = nt_D;

    hipMemsetAsync(vent, 0, ventBytes, stream);
    hipMemsetAsync(meta, 0, 4096, stream);

    const int qblocks = NQUAD_ / 256;  // 1936, exact
    hist_kernel<<<dim3(qblocks), dim3(256), 0, stream>>>(gp, hist);
    scan_kernel<<<dim3(1), dim3(256), 0, stream>>>(hist, itemOff, bstart);
    scatter_kernel<<<dim3(qblocks), dim3(256), 0, stream>>>(gp, itemOff, cursor, items);
    rgcn_gemm_kernel<<<dim3(MAXBLK_), dim3(256), 0, stream>>>(
        gp, entity_emb, entity_ctx, egw, items, itemOff, bstart, vent);

    const size_t cs = (size_t)B_ * M1_ * DIM_;
    gcnrel_kernel<<<dim3(B_), dim3(128), 0, stream>>>(relation_emb, relation_ctx, rgw, pos_r, pr_adj, pr_A, vrel + 0 * cs);
    gcnrel_kernel<<<dim3(B_), dim3(128), 0, stream>>>(relation_emb, relation_ctx, rgw, neg_r, nr_adj, nr_A, vrel + 1 * cs);
    final_kernel<<<dim3(B_), dim3(128), 0, stream>>>(entity_emb, relation_emb,
        pos_h, pos_r, pos_t, neg_h, neg_r, neg_t,
        ph_nn, pt_nn, nh_nn, nt_nn,
        gate_e, gate_r, v_ent, v_rel, vent, vrel, (float*)d_out);
}

// Round 3
// 284.360 us; speedup vs baseline: 3.6479x; 2.1535x over previous
//
#include <hip/hip_runtime.h>
#include <math.h>

#define B_   1024
#define M_   10
#define M1_  11
#define DIM_ 128
#define NW_  201                    // real weight rows; r >= 201 -> zero matrix
#define NQUAD_ (4*B_*M1_*M1_)       // 495616 (case,b,j,k) quadruples
#define IPB_  32                    // items per GEMM block
#define MAXCH_ ((NQUAD_ + IPB_ - 1)/IPB_)
#define MAXBLK_ (NW_ + MAXCH_)

typedef _Float16 f16x4 __attribute__((ext_vector_type(4)));

struct GatherPtrs {
    const int* center[4];
    const int* adj[4];
    const int* nn[4];
    const int* Rt[4];
    const float* Dm[4];
};

struct RelPtrs {
    const int* center[2];
    const int* adj2[2];
    const float* A[2];
};

// ---------------------------------------------------------------------------
// Pass 1: histogram via LDS (121 blocks x 1024 thr x 4 quads = exactly NQUAD_)
// ---------------------------------------------------------------------------
__global__ __launch_bounds__(1024)
void hist_kernel(GatherPtrs gp, int* __restrict__ hist)
{
    __shared__ int lh[NW_];
    const int tid = threadIdx.x;
    if (tid < NW_) lh[tid] = 0;
    __syncthreads();
    #pragma unroll
    for (int s = 0; s < 4; ++s) {
        const int idx = blockIdx.x * 4096 + s * 1024 + tid;
        const int c = idx / (B_ * M1_ * M1_);
        const int rem = idx % (B_ * M1_ * M1_);
        const int b = rem / (M1_ * M1_);
        const int jk = rem % (M1_ * M1_);
        const int j = jk / M1_, k = jk % M1_;
        const int n = gp.nn[c][b];
        if (j <= n && k <= n) {
            const int r = gp.Rt[c][rem];
            if (r < NW_) atomicAdd(&lh[r], 1);
        }
    }
    __syncthreads();
    if (tid < NW_ && lh[tid]) atomicAdd(&hist[tid], lh[tid]);
}

// ---------------------------------------------------------------------------
// Pass 2: exclusive prefix sums — single block
// ---------------------------------------------------------------------------
__global__ __launch_bounds__(256)
void scan_kernel(const int* __restrict__ hist, int* __restrict__ itemOff,
                 int* __restrict__ bstart)
{
    __shared__ int h[NW_];
    __shared__ int io[NW_ + 1];
    __shared__ int bs[NW_ + 1];
    const int t = threadIdx.x;
    if (t < NW_) h[t] = hist[t];
    __syncthreads();
    if (t == 0) {
        int accI = 0, accB = 0;
        for (int i = 0; i < NW_; ++i) {
            io[i] = accI; bs[i] = accB;
            accI += h[i]; accB += (h[i] + IPB_ - 1) / IPB_;
        }
        io[NW_] = accI; bs[NW_] = accB;
    }
    __syncthreads();
    if (t <= NW_) { itemOff[t] = io[t]; bstart[t] = bs[t]; }
}

// ---------------------------------------------------------------------------
// Pass 3: scatter with LDS ranking (one global atomic per (block, t))
// ---------------------------------------------------------------------------
__global__ __launch_bounds__(1024)
void scatter_kernel(GatherPtrs gp, const int* __restrict__ itemOff,
                    int* __restrict__ cursor, int* __restrict__ items)
{
    __shared__ int lh[NW_];
    __shared__ int lbase[NW_];
    const int tid = threadIdx.x;
    if (tid < NW_) lh[tid] = 0;
    __syncthreads();
    int rr[4], rk[4], pk[4];
    #pragma unroll
    for (int s = 0; s < 4; ++s) {
        const int idx = blockIdx.x * 4096 + s * 1024 + tid;
        const int c = idx / (B_ * M1_ * M1_);
        const int rem = idx % (B_ * M1_ * M1_);
        const int b = rem / (M1_ * M1_);
        const int jk = rem % (M1_ * M1_);
        const int j = jk / M1_, k = jk % M1_;
        const int n = gp.nn[c][b];
        rr[s] = -1;
        if (j <= n && k <= n) {
            const int r = gp.Rt[c][rem];
            if (r < NW_) {
                rr[s] = r;
                rk[s] = atomicAdd(&lh[r], 1);
                pk[s] = (c << 18) | (b << 8) | (j << 4) | k;
            }
        }
    }
    __syncthreads();
    if (tid < NW_) lbase[tid] = lh[tid] ? atomicAdd(&cursor[tid], lh[tid]) : 0;
    __syncthreads();
    #pragma unroll
    for (int s = 0; s < 4; ++s)
        if (rr[s] >= 0) items[itemOff[rr[s]] + lbase[rr[s]] + rk[s]] = pk[s];
}

// ---------------------------------------------------------------------------
// Grouped-GEMM core (shared by fast/atomic epilogues)
// ---------------------------------------------------------------------------
__device__ __forceinline__
void gemm_core(const GatherPtrs& gp,
               const float* __restrict__ ent_emb,
               const float* __restrict__ ent_ctx,
               const float* __restrict__ W,
               const int* __restrict__ items,
               const int* __restrict__ itemOff,
               const int* __restrict__ bstart,
               float4* sWv, float4* sHv,
               int& istart, int& nItems, float acc[4][4])
{
    const int bid = blockIdx.x;
    // binary search: largest t with bstart[t] <= bid
    int lo = 0, hi = NW_;
    while (lo + 1 < hi) { const int mid = (lo + hi) >> 1; if (bstart[mid] <= bid) lo = mid; else hi = mid; }
    const int t = lo;
    istart = itemOff[t] + (bid - bstart[t]) * IPB_;
    nItems = min(IPB_, itemOff[t + 1] - istart);
    const int tid = threadIdx.x;

    const float4* Wg = (const float4*)(W + (size_t)t * DIM_ * DIM_);
    #pragma unroll
    for (int i = 0; i < 16; ++i) sWv[i * 256 + tid] = Wg[i * 256 + tid];

    {
        const int it = tid >> 3, part = tid & 7;
        float4* dst = sHv + it * (DIM_ / 4);
        if (it < nItems) {
            const int p = items[istart + it];
            const int c = p >> 18, b = (p >> 8) & 1023, j = (p >> 4) & 15, k = p & 15;
            const float* src = (j == 0)
                ? ent_emb + (size_t)gp.center[c][b] * DIM_
                : ent_ctx + (size_t)gp.adj[c][b * M_ + (j - 1)] * DIM_;
            const float d = gp.Dm[c][(b * M1_ + j) * M1_ + k];
            const float4* s4 = (const float4*)src;
            #pragma unroll
            for (int s = 0; s < 4; ++s) {
                float4 v = s4[part * 4 + s];
                v.x *= d; v.y *= d; v.z *= d; v.w *= d;
                dst[part * 4 + s] = v;
            }
        } else {
            const float4 z = {0.f, 0.f, 0.f, 0.f};
            #pragma unroll
            for (int s = 0; s < 4; ++s) dst[part * 4 + s] = z;
        }
    }
    __syncthreads();

    const int q = tid & 31, g = tid >> 5;
    #pragma unroll 2
    for (int d0 = 0; d0 < DIM_; d0 += 4) {
        const float4 w0 = sWv[(d0 + 0) * 32 + q];
        const float4 w1 = sWv[(d0 + 1) * 32 + q];
        const float4 w2 = sWv[(d0 + 2) * 32 + q];
        const float4 w3 = sWv[(d0 + 3) * 32 + q];
        #pragma unroll
        for (int m = 0; m < 4; ++m) {
            const float4 h = sHv[(4 * g + m) * 32 + (d0 >> 2)];
            acc[m][0] += h.x * w0.x + h.y * w1.x + h.z * w2.x + h.w * w3.x;
            acc[m][1] += h.x * w0.y + h.y * w1.y + h.z * w2.y + h.w * w3.y;
            acc[m][2] += h.x * w0.z + h.y * w1.z + h.z * w2.z + h.w * w3.z;
            acc[m][3] += h.x * w0.w + h.y * w1.w + h.z * w2.w + h.w * w3.w;
        }
    }
}

// Fast epilogue: non-atomic fp16 store at the item's quadruple index.
__global__ __launch_bounds__(256, 1)
void rgcn_gemm_fast(GatherPtrs gp,
                    const float* __restrict__ ent_emb,
                    const float* __restrict__ ent_ctx,
                    const float* __restrict__ W,
                    const int* __restrict__ items,
                    const int* __restrict__ itemOff,
                    const int* __restrict__ bstart,
                    _Float16* __restrict__ partial)
{
    __shared__ float4 sWv[DIM_ * DIM_ / 4];
    __shared__ float4 sHv[IPB_ * DIM_ / 4];
    if (blockIdx.x >= bstart[NW_]) return;
    int istart, nItems;
    float acc[4][4] = {};
    gemm_core(gp, ent_emb, ent_ctx, W, items, itemOff, bstart, sWv, sHv, istart, nItems, acc);

    const int q = threadIdx.x & 31, g = threadIdx.x >> 5;
    #pragma unroll
    for (int m = 0; m < 4; ++m) {
        const int it = 4 * g + m;
        if (it < nItems) {
            const int p = items[istart + it];
            const int c = p >> 18, b = (p >> 8) & 1023, j = (p >> 4) & 15, k = p & 15;
            const size_t qidx = ((size_t)((c * B_ + b) * M1_ + j)) * M1_ + k;
            f16x4 st;
            st.x = (_Float16)acc[m][0]; st.y = (_Float16)acc[m][1];
            st.z = (_Float16)acc[m][2]; st.w = (_Float16)acc[m][3];
            *reinterpret_cast<f16x4*>(partial + qidx * DIM_ + 4 * q) = st;
        }
    }
}

// Fallback epilogue: f32 global atomics into vent (round-2 proven path).
__global__ __launch_bounds__(256, 1)
void rgcn_gemm_atomic(GatherPtrs gp,
                      const float* __restrict__ ent_emb,
                      const float* __restrict__ ent_ctx,
                      const float* __restrict__ W,
                      const int* __restrict__ items,
                      const int* __restrict__ itemOff,
                      const int* __restrict__ bstart,
                      float* __restrict__ vent)
{
    __shared__ float4 sWv[DIM_ * DIM_ / 4];
    __shared__ float4 sHv[IPB_ * DIM_ / 4];
    if (blockIdx.x >= bstart[NW_]) return;
    int istart, nItems;
    float acc[4][4] = {};
    gemm_core(gp, ent_emb, ent_ctx, W, items, itemOff, bstart, sWv, sHv, istart, nItems, acc);

    const int q = threadIdx.x & 31, g = threadIdx.x >> 5;
    #pragma unroll
    for (int m = 0; m < 4; ++m) {
        const int it = 4 * g + m;
        if (it < nItems) {
            const int p = items[istart + it];
            const int c = p >> 18, b = (p >> 8) & 1023, j = (p >> 4) & 15;
            float* dstp = vent + (((size_t)(c * B_ + b)) * M1_ + j) * DIM_ + 4 * q;
            unsafeAtomicAdd(dstp + 0, acc[m][0]);
            unsafeAtomicAdd(dstp + 1, acc[m][1]);
            unsafeAtomicAdd(dstp + 2, acc[m][2]);
            unsafeAtomicAdd(dstp + 3, acc[m][3]);
        }
    }
}

// ---------------------------------------------------------------------------
// Relation GCN, both cases fused via blockIdx.y
// ---------------------------------------------------------------------------
__global__ __launch_bounds__(128)
void gcnrel_kernel(const float* __restrict__ rel_emb,
                   const float* __restrict__ rel_ctx,
                   const float* __restrict__ Wr,
                   RelPtrs rp,
                   float* __restrict__ vrel)
{
    __shared__ float sH[M1_][DIM_];
    __shared__ float sAH[M1_][DIM_];
    __shared__ float sA[M1_ * M1_];
    const int b = blockIdx.x;
    const int cse = blockIdx.y;
    const int e = threadIdx.x;
    const int* adj2 = rp.adj2[cse];

    sH[0][e] = rel_emb[(size_t)rp.center[cse][b] * DIM_ + e];
    #pragma unroll
    for (int j = 1; j < M1_; ++j) {
        const int a0 = adj2[((b * M_) + (j - 1)) * 2 + 0];
        const int a1 = adj2[((b * M_) + (j - 1)) * 2 + 1];
        sH[j][e] = rel_ctx[(size_t)a0 * DIM_ + e] + rel_ctx[(size_t)a1 * DIM_ + e];
    }
    if (e < M1_ * M1_) sA[e] = rp.A[cse][b * (M1_ * M1_) + e];
    __syncthreads();

    #pragma unroll
    for (int i = 0; i < M1_; ++i) {
        float s = 0.f;
        #pragma unroll
        for (int jj = 0; jj < M1_; ++jj) s += sA[i * M1_ + jj] * sH[jj][e];
        sAH[i][e] = s;
    }
    __syncthreads();

    float acc[M1_];
    #pragma unroll
    for (int i = 0; i < M1_; ++i) acc[i] = 0.f;
    for (int d = 0; d < DIM_; ++d) {
        const float w = Wr[d * DIM_ + e];
        #pragma unroll
        for (int i = 0; i < M1_; ++i) acc[i] += sAH[i][d] * w;
    }
    float* outp = vrel + ((size_t)cse * B_ + b) * (M1_ * DIM_);
    #pragma unroll
    for (int i = 0; i < M1_; ++i) outp[i * DIM_ + e] = fmaxf(acc[i], 0.f);
}

// ---------------------------------------------------------------------------
// Final: (fast: gather partial sums) attention + gating + L2 score
// ---------------------------------------------------------------------------
__device__ __forceinline__ float reduce128(float x, float* red) {
    #pragma unroll
    for (int o = 32; o > 0; o >>= 1) x += __shfl_down(x, o, 64);
    __syncthreads();
    if ((threadIdx.x & 63) == 0) red[threadIdx.x >> 6] = x;
    __syncthreads();
    return red[0] + red[1];
}

__device__ float subgraph_from_vm(const float* vm, float o, float ve, float* red) {
    float sc[M1_];
    #pragma unroll
    for (int j = 0; j < M1_; ++j)
        sc[j] = reduce128(fmaxf(vm[j] * o, 0.f) * ve, red);
    float mx = sc[0];
    #pragma unroll
    for (int j = 1; j < M1_; ++j) mx = fmaxf(mx, sc[j]);
    float s = 0.f;
    float ex[M1_];
    #pragma unroll
    for (int j = 0; j < M1_; ++j) { ex[j] = expf(sc[j] - mx); s += ex[j]; }
    const float inv = 1.f / s;
    float sg = 0.f;
    #pragma unroll
    for (int j = 0; j < M1_; ++j) sg += ex[j] * inv * vm[j];
    return sg;
}

template <bool FAST>
__global__ __launch_bounds__(128)
void final_kernel(GatherPtrs gp,
                  const float* __restrict__ ent_emb,
                  const float* __restrict__ rel_emb,
                  const int* __restrict__ pos_r, const int* __restrict__ neg_r,
                  const float* __restrict__ gate_e, const float* __restrict__ gate_r,
                  const float* __restrict__ v_ent, const float* __restrict__ v_rel,
                  const _Float16* __restrict__ partial,  // FAST
                  const float* __restrict__ vent,        // !FAST
                  const float* __restrict__ vrel,
                  float* __restrict__ out)
{
    __shared__ float red[2];
    __shared__ int sRt[4][M1_ * M1_];
    __shared__ int snn[4];
    const int b = blockIdx.x;
    const int e = threadIdx.x;

    if (FAST) {
        if (e < M1_ * M1_) {
            #pragma unroll
            for (int c = 0; c < 4; ++c) sRt[c][e] = gp.Rt[c][b * (M1_ * M1_) + e];
        }
    }
    if (e < 4) snn[e] = gp.nn[e][b];
    __syncthreads();

    const float ve = v_ent[e], vr = v_rel[e];
    const size_t cs = (size_t)B_ * M1_ * DIM_;
    const size_t bo = (size_t)b * M1_ * DIM_;

    float osg[4], cvec[4];
    #pragma unroll
    for (int c = 0; c < 4; ++c) {
        const float o = ent_emb[(size_t)gp.center[c][b] * DIM_ + e];
        cvec[c] = o;
        const int n = snn[c];
        float vm[M1_];
        if (FAST) {
            #pragma unroll
            for (int j = 0; j < M1_; ++j) {
                float s = 0.f;
                if (j <= n) {
                    const int base = (c * B_ + b) * (M1_ * M1_) + j * M1_;
                    for (int k = 0; k <= n; ++k) {
                        const int r = sRt[c][j * M1_ + k];
                        if (r < NW_) s += (float)partial[(size_t)(base + k) * DIM_ + e];
                    }
                    s = fmaxf(s, 0.f);
                }
                vm[j] = s;
            }
        } else {
            const float* vmat = vent + c * cs + bo;
            #pragma unroll
            for (int j = 0; j < M1_; ++j) {
                const float raw = vmat[j * DIM_ + e];
                vm[j] = (j <= n) ? fmaxf(raw, 0.f) : 0.f;
            }
        }
        osg[c] = subgraph_from_vm(vm, o, ve, red);
    }

    float rsg[2], rvec[2];
    #pragma unroll
    for (int c = 0; c < 2; ++c) {
        const int* ridx = (c == 0) ? pos_r : neg_r;
        const float o = rel_emb[(size_t)ridx[b] * DIM_ + e];
        rvec[c] = o;
        const float* vmat = vrel + c * cs + bo;
        float vm[M1_];
        #pragma unroll
        for (int j = 0; j < M1_; ++j) vm[j] = vmat[j * DIM_ + e];
        rsg[c] = subgraph_from_vm(vm, o, vr, red);
    }

    const float ge = 1.f / (1.f + expf(-gate_e[e]));
    const float gr = 1.f / (1.f + expf(-gate_r[e]));
    const float ph_o = ge * cvec[0] + (1.f - ge) * osg[0];
    const float pt_o = ge * cvec[1] + (1.f - ge) * osg[1];
    const float nh_o = ge * cvec[2] + (1.f - ge) * osg[2];
    const float nt_o = ge * cvec[3] + (1.f - ge) * osg[3];
    const float pr_o = gr * rvec[0] + (1.f - gr) * rsg[0];
    const float nr_o = gr * rvec[1] + (1.f - gr) * rsg[1];

    const float pv = ph_o + pr_o - pt_o;
    const float ps2 = reduce128(pv * pv, red);
    const float nv = nh_o + nr_o - nt_o;
    const float ns2 = reduce128(nv * nv, red);
    if (e == 0) { out[b] = sqrtf(ps2); out[B_ + b] = sqrtf(ns2); }
}

extern "C" void kernel_launch(void* const* d_in, const int* in_sizes, int n_in,
                              void* d_out, int out_size, void* d_ws, size_t ws_size,
                              hipStream_t stream)
{
    const float* entity_emb   = (const float*)d_in[0];
    const float* relation_emb = (const float*)d_in[1];
    const float* entity_ctx   = (const float*)d_in[2];
    const float* relation_ctx = (const float*)d_in[3];
    const float* egw          = (const float*)d_in[4];
    const float* rgw          = (const float*)d_in[5];
    const float* gate_e       = (const float*)d_in[6];
    const float* gate_r       = (const float*)d_in[7];
    const float* v_ent        = (const float*)d_in[8];
    const float* v_rel        = (const float*)d_in[9];
    const int* pos_h = (const int*)d_in[10];
    const int* pos_r = (const int*)d_in[11];
    const int* pos_t = (const int*)d_in[12];
    const int* neg_h = (const int*)d_in[13];
    const int* neg_r = (const int*)d_in[14];
    const int* neg_t = (const int*)d_in[15];
    const int* ph_adj = (const int*)d_in[16];
    const int* pt_adj = (const int*)d_in[17];
    const int* nh_adj = (const int*)d_in[18];
    const int* nt_adj = (const int*)d_in[19];
    const int* pr_adj = (const int*)d_in[20];
    const int* nr_adj = (const int*)d_in[21];
    const int* ph_R = (const int*)d_in[22];
    const int* pt_R = (const int*)d_in[23];
    const int* nh_R = (const int*)d_in[24];
    const int* nt_R = (const int*)d_in[25];
    const int* ph_nn = (const int*)d_in[26];
    const int* pt_nn = (const int*)d_in[27];
    const int* nh_nn = (const int*)d_in[28];
    const int* nt_nn = (const int*)d_in[29];
    const float* ph_D = (const float*)d_in[30];
    const float* pt_D = (const float*)d_in[31];
    const float* nh_D = (const float*)d_in[32];
    const float* nt_D = (const float*)d_in[33];
    const float* pr_A = (const float*)d_in[34];
    const float* nr_A = (const float*)d_in[35];

    GatherPtrs gp;
    gp.center[0] = pos_h; gp.center[1] = pos_t; gp.center[2] = neg_h; gp.center[3] = neg_t;
    gp.adj[0] = ph_adj; gp.adj[1] = pt_adj; gp.adj[2] = nh_adj; gp.adj[3] = nt_adj;
    gp.nn[0] = ph_nn; gp.nn[1] = pt_nn; gp.nn[2] = nh_nn; gp.nn[3] = nt_nn;
    gp.Rt[0] = ph_R; gp.Rt[1] = pt_R; gp.Rt[2] = nh_R; gp.Rt[3] = nt_R;
    gp.Dm[0] = ph_D; gp.Dm[1] = pt_D; gp.Dm[2] = nh_D; gp.Dm[3] = nt_D;

    RelPtrs rp;
    rp.center[0] = pos_r; rp.center[1] = neg_r;
    rp.adj2[0] = pr_adj; rp.adj2[1] = nr_adj;
    rp.A[0] = pr_A; rp.A[1] = nr_A;

    char* wsb = (char*)d_ws;
    const size_t partialBytes = (size_t)NQUAD_ * DIM_ * 2;      // 126,877,696
    const size_t itemsBytes   = (size_t)NQUAD_ * 4;             //   1,982,464
    const size_t vrelBytes    = (size_t)2 * B_ * M1_ * DIM_ * 4;//  11,534,336
    const size_t fastNeed = partialBytes + itemsBytes + 4096 + vrelBytes;
    const bool fast = (ws_size >= fastNeed);

    if (fast) {
        _Float16* partial = (_Float16*)wsb;
        int* items = (int*)(wsb + partialBytes);
        int* meta  = (int*)(wsb + partialBytes + itemsBytes);
        float* vrel = (float*)(wsb + partialBytes + itemsBytes + 4096);
        int* hist    = meta;
        int* itemOff = meta + 256;
        int* bstart  = meta + 512;
        int* cursor  = meta + 768;

        hipMemsetAsync(meta, 0, 4096, stream);
        hist_kernel<<<dim3(121), dim3(1024), 0, stream>>>(gp, hist);
        scan_kernel<<<dim3(1), dim3(256), 0, stream>>>(hist, itemOff, bstart);
        scatter_kernel<<<dim3(121), dim3(1024), 0, stream>>>(gp, itemOff, cursor, items);
        rgcn_gemm_fast<<<dim3(MAXBLK_), dim3(256), 0, stream>>>(
            gp, entity_emb, entity_ctx, egw, items, itemOff, bstart, partial);
        gcnrel_kernel<<<dim3(B_, 2), dim3(128), 0, stream>>>(relation_emb, relation_ctx, rgw, rp, vrel);
        final_kernel<true><<<dim3(B_), dim3(128), 0, stream>>>(gp, entity_emb, relation_emb,
            pos_r, neg_r, gate_e, gate_r, v_ent, v_rel, partial, nullptr, vrel, (float*)d_out);
    } else {
        // round-2 proven fallback: atomic accumulation into vent
        float* vent = (float*)wsb;
        const size_t ventBytes = (size_t)4 * B_ * M1_ * DIM_ * 4;  // 23,068,672
        float* vrel = (float*)(wsb + ventBytes);
        int* items = (int*)(wsb + ventBytes);                       // aliased; consumed pre-gcnrel
        int* meta  = (int*)(wsb + ventBytes + (8u << 20));
        int* hist    = meta;
        int* itemOff = meta + 256;
        int* bstart  = meta + 512;
        int* cursor  = meta + 768;

        hipMemsetAsync(vent, 0, ventBytes, stream);
        hipMemsetAsync(meta, 0, 4096, stream);
        hist_kernel<<<dim3(121), dim3(1024), 0, stream>>>(gp, hist);
        scan_kernel<<<dim3(1), dim3(256), 0, stream>>>(hist, itemOff, bstart);
        scatter_kernel<<<dim3(121), dim3(1024), 0, stream>>>(gp, itemOff, cursor, items);
        rgcn_gemm_atomic<<<dim3(MAXBLK_), dim3(256), 0, stream>>>(
            gp, entity_emb, entity_ctx, egw, items, itemOff, bstart, vent);
        gcnrel_kernel<<<dim3(B_, 2), dim3(128), 0, stream>>>(relation_emb, relation_ctx, rgw, rp, vrel);
        final_kernel<false><<<dim3(B_), dim3(128), 0, stream>>>(gp, entity_emb, relation_emb,
            pos_r, neg_r, gate_e, gate_r, v_ent, v_rel, nullptr, vent, vrel, (float*)d_out);
    }
}

// Round 4
// 192.622 us; speedup vs baseline: 5.3852x; 1.4763x over previous
//
#include <hip/hip_runtime.h>
#include <math.h>

#define B_   1024
#define M_   10
#define M1_  11
#define DIM_ 128
#define NW_  201                    // real weight rows; r >= 201 -> zero matrix
#define NQUAD_ (4*B_*M1_*M1_)       // 495616 (case,b,j,k) quadruples
#define IPB_  32                    // items per GEMM block
#define MAXCH_ ((NQUAD_ + IPB_ - 1)/IPB_)
#define MAXBLK_ (NW_ + MAXCH_)

typedef _Float16 f16x4 __attribute__((ext_vector_type(4)));

struct GatherPtrs {
    const int* center[4];
    const int* adj[4];
    const int* nn[4];
    const int* Rt[4];
    const float* Dm[4];
};

struct RelPtrs {
    const int* center[2];
    const int* adj2[2];
    const float* A[2];
};

// ---------------------------------------------------------------------------
// Batched cross-wave reduction: sum p[N] over 128 threads, result broadcast.
// One barrier total (vs N serial reductions x 2 barriers).
// ---------------------------------------------------------------------------
template <int N>
__device__ __forceinline__ void block_reduce_bcast(float (&p)[N], float (*sred)[N],
                                                   int e, float (&sc)[N])
{
    #pragma unroll
    for (int off = 32; off; off >>= 1)
        #pragma unroll
        for (int i = 0; i < N; ++i) p[i] += __shfl_xor(p[i], off, 64);
    if ((e & 63) == 0) {
        #pragma unroll
        for (int i = 0; i < N; ++i) sred[e >> 6][i] = p[i];
    }
    __syncthreads();
    #pragma unroll
    for (int i = 0; i < N; ++i) sc[i] = sred[0][i] + sred[1][i];
}

// attention-pool: given vm[11] per (thread e), center o, key ve -> sg[e]
__device__ __forceinline__ float attn_pool(const float (&vm)[M1_], float o, float ve,
                                           float (*sred)[M1_], int e)
{
    float p[M1_];
    #pragma unroll
    for (int j = 0; j < M1_; ++j) p[j] = fmaxf(vm[j] * o, 0.f) * ve;
    float sc[M1_];
    block_reduce_bcast<M1_>(p, sred, e, sc);
    float mx = sc[0];
    #pragma unroll
    for (int j = 1; j < M1_; ++j) mx = fmaxf(mx, sc[j]);
    float s = 0.f, ex[M1_];
    #pragma unroll
    for (int j = 0; j < M1_; ++j) { ex[j] = expf(sc[j] - mx); s += ex[j]; }
    const float inv = 1.f / s;
    float sg = 0.f;
    #pragma unroll
    for (int j = 0; j < M1_; ++j) sg += ex[j] * inv * vm[j];
    return sg;
}

// ---------------------------------------------------------------------------
// Pass 1: histogram via LDS
// ---------------------------------------------------------------------------
__global__ __launch_bounds__(1024)
void hist_kernel(GatherPtrs gp, int* __restrict__ hist)
{
    __shared__ int lh[NW_];
    const int tid = threadIdx.x;
    if (tid < NW_) lh[tid] = 0;
    __syncthreads();
    #pragma unroll
    for (int s = 0; s < 4; ++s) {
        const int idx = blockIdx.x * 4096 + s * 1024 + tid;
        const int c = idx / (B_ * M1_ * M1_);
        const int rem = idx % (B_ * M1_ * M1_);
        const int b = rem / (M1_ * M1_);
        const int jk = rem % (M1_ * M1_);
        const int j = jk / M1_, k = jk % M1_;
        const int n = gp.nn[c][b];
        if (j <= n && k <= n) {
            const int r = gp.Rt[c][rem];
            if (r < NW_) atomicAdd(&lh[r], 1);
        }
    }
    __syncthreads();
    if (tid < NW_ && lh[tid]) atomicAdd(&hist[tid], lh[tid]);
}

// ---------------------------------------------------------------------------
// Pass 2: exclusive prefix sums — single block
// ---------------------------------------------------------------------------
__global__ __launch_bounds__(256)
void scan_kernel(const int* __restrict__ hist, int* __restrict__ itemOff,
                 int* __restrict__ bstart)
{
    __shared__ int h[NW_];
    __shared__ int io[NW_ + 1];
    __shared__ int bs[NW_ + 1];
    const int t = threadIdx.x;
    if (t < NW_) h[t] = hist[t];
    __syncthreads();
    if (t == 0) {
        int accI = 0, accB = 0;
        for (int i = 0; i < NW_; ++i) {
            io[i] = accI; bs[i] = accB;
            accI += h[i]; accB += (h[i] + IPB_ - 1) / IPB_;
        }
        io[NW_] = accI; bs[NW_] = accB;
    }
    __syncthreads();
    if (t <= NW_) { itemOff[t] = io[t]; bstart[t] = bs[t]; }
}

// ---------------------------------------------------------------------------
// Pass 3: scatter with LDS ranking
// ---------------------------------------------------------------------------
__global__ __launch_bounds__(1024)
void scatter_kernel(GatherPtrs gp, const int* __restrict__ itemOff,
                    int* __restrict__ cursor, int* __restrict__ items)
{
    __shared__ int lh[NW_];
    __shared__ int lbase[NW_];
    const int tid = threadIdx.x;
    if (tid < NW_) lh[tid] = 0;
    __syncthreads();
    int rr[4], rk[4], pk[4];
    #pragma unroll
    for (int s = 0; s < 4; ++s) {
        const int idx = blockIdx.x * 4096 + s * 1024 + tid;
        const int c = idx / (B_ * M1_ * M1_);
        const int rem = idx % (B_ * M1_ * M1_);
        const int b = rem / (M1_ * M1_);
        const int jk = rem % (M1_ * M1_);
        const int j = jk / M1_, k = jk % M1_;
        const int n = gp.nn[c][b];
        rr[s] = -1;
        if (j <= n && k <= n) {
            const int r = gp.Rt[c][rem];
            if (r < NW_) {
                rr[s] = r;
                rk[s] = atomicAdd(&lh[r], 1);
                pk[s] = (c << 18) | (b << 8) | (j << 4) | k;
            }
        }
    }
    __syncthreads();
    if (tid < NW_) lbase[tid] = lh[tid] ? atomicAdd(&cursor[tid], lh[tid]) : 0;
    __syncthreads();
    #pragma unroll
    for (int s = 0; s < 4; ++s)
        if (rr[s] >= 0) items[itemOff[rr[s]] + lbase[rr[s]] + rk[s]] = pk[s];
}

// ---------------------------------------------------------------------------
// Grouped-GEMM core
// ---------------------------------------------------------------------------
__device__ __forceinline__
void gemm_core(const GatherPtrs& gp,
               const float* __restrict__ ent_emb,
               const float* __restrict__ ent_ctx,
               const float* __restrict__ W,
               const int* __restrict__ items,
               const int* __restrict__ itemOff,
               const int* __restrict__ bstart,
               float4* sWv, float4* sHv,
               int& istart, int& nItems, float acc[4][4])
{
    const int bid = blockIdx.x;
    int lo = 0, hi = NW_;
    while (lo + 1 < hi) { const int mid = (lo + hi) >> 1; if (bstart[mid] <= bid) lo = mid; else hi = mid; }
    const int t = lo;
    istart = itemOff[t] + (bid - bstart[t]) * IPB_;
    nItems = min(IPB_, itemOff[t + 1] - istart);
    const int tid = threadIdx.x;

    const float4* Wg = (const float4*)(W + (size_t)t * DIM_ * DIM_);
    #pragma unroll
    for (int i = 0; i < 16; ++i) sWv[i * 256 + tid] = Wg[i * 256 + tid];

    {
        const int it = tid >> 3, part = tid & 7;
        float4* dst = sHv + it * (DIM_ / 4);
        if (it < nItems) {
            const int p = items[istart + it];
            const int c = p >> 18, b = (p >> 8) & 1023, j = (p >> 4) & 15, k = p & 15;
            const float* src = (j == 0)
                ? ent_emb + (size_t)gp.center[c][b] * DIM_
                : ent_ctx + (size_t)gp.adj[c][b * M_ + (j - 1)] * DIM_;
            const float d = gp.Dm[c][(b * M1_ + j) * M1_ + k];
            const float4* s4 = (const float4*)src;
            #pragma unroll
            for (int s = 0; s < 4; ++s) {
                float4 v = s4[part * 4 + s];
                v.x *= d; v.y *= d; v.z *= d; v.w *= d;
                dst[part * 4 + s] = v;
            }
        } else {
            const float4 z = {0.f, 0.f, 0.f, 0.f};
            #pragma unroll
            for (int s = 0; s < 4; ++s) dst[part * 4 + s] = z;
        }
    }
    __syncthreads();

    const int q = tid & 31, g = tid >> 5;
    #pragma unroll 2
    for (int d0 = 0; d0 < DIM_; d0 += 4) {
        const float4 w0 = sWv[(d0 + 0) * 32 + q];
        const float4 w1 = sWv[(d0 + 1) * 32 + q];
        const float4 w2 = sWv[(d0 + 2) * 32 + q];
        const float4 w3 = sWv[(d0 + 3) * 32 + q];
        #pragma unroll
        for (int m = 0; m < 4; ++m) {
            const float4 h = sHv[(4 * g + m) * 32 + (d0 >> 2)];
            acc[m][0] += h.x * w0.x + h.y * w1.x + h.z * w2.x + h.w * w3.x;
            acc[m][1] += h.x * w0.y + h.y * w1.y + h.z * w2.y + h.w * w3.y;
            acc[m][2] += h.x * w0.z + h.y * w1.z + h.z * w2.z + h.w * w3.z;
            acc[m][3] += h.x * w0.w + h.y * w1.w + h.z * w2.w + h.w * w3.w;
        }
    }
}

// Fast epilogue: non-atomic fp16 store at the item's quadruple index.
__global__ __launch_bounds__(256, 1)
void rgcn_gemm_fast(GatherPtrs gp,
                    const float* __restrict__ ent_emb,
                    const float* __restrict__ ent_ctx,
                    const float* __restrict__ W,
                    const int* __restrict__ items,
                    const int* __restrict__ itemOff,
                    const int* __restrict__ bstart,
                    _Float16* __restrict__ partial)
{
    __shared__ float4 sWv[DIM_ * DIM_ / 4];
    __shared__ float4 sHv[IPB_ * DIM_ / 4];
    if (blockIdx.x >= bstart[NW_]) return;
    int istart, nItems;
    float acc[4][4] = {};
    gemm_core(gp, ent_emb, ent_ctx, W, items, itemOff, bstart, sWv, sHv, istart, nItems, acc);

    const int q = threadIdx.x & 31, g = threadIdx.x >> 5;
    #pragma unroll
    for (int m = 0; m < 4; ++m) {
        const int it = 4 * g + m;
        if (it < nItems) {
            const int p = items[istart + it];
            const int c = p >> 18, b = (p >> 8) & 1023, j = (p >> 4) & 15, k = p & 15;
            const size_t qidx = ((size_t)((c * B_ + b) * M1_ + j)) * M1_ + k;
            f16x4 st;
            st.x = (_Float16)acc[m][0]; st.y = (_Float16)acc[m][1];
            st.z = (_Float16)acc[m][2]; st.w = (_Float16)acc[m][3];
            *reinterpret_cast<f16x4*>(partial + qidx * DIM_ + 4 * q) = st;
        }
    }
}

// Fallback epilogue: f32 global atomics into vent.
__global__ __launch_bounds__(256, 1)
void rgcn_gemm_atomic(GatherPtrs gp,
                      const float* __restrict__ ent_emb,
                      const float* __restrict__ ent_ctx,
                      const float* __restrict__ W,
                      const int* __restrict__ items,
                      const int* __restrict__ itemOff,
                      const int* __restrict__ bstart,
                      float* __restrict__ vent)
{
    __shared__ float4 sWv[DIM_ * DIM_ / 4];
    __shared__ float4 sHv[IPB_ * DIM_ / 4];
    if (blockIdx.x >= bstart[NW_]) return;
    int istart, nItems;
    float acc[4][4] = {};
    gemm_core(gp, ent_emb, ent_ctx, W, items, itemOff, bstart, sWv, sHv, istart, nItems, acc);

    const int q = threadIdx.x & 31, g = threadIdx.x >> 5;
    #pragma unroll
    for (int m = 0; m < 4; ++m) {
        const int it = 4 * g + m;
        if (it < nItems) {
            const int p = items[istart + it];
            const int c = p >> 18, b = (p >> 8) & 1023, j = (p >> 4) & 15;
            float* dstp = vent + (((size_t)(c * B_ + b)) * M1_ + j) * DIM_ + 4 * q;
            unsafeAtomicAdd(dstp + 0, acc[m][0]);
            unsafeAtomicAdd(dstp + 1, acc[m][1]);
            unsafeAtomicAdd(dstp + 2, acc[m][2]);
            unsafeAtomicAdd(dstp + 3, acc[m][3]);
        }
    }
}

// ---------------------------------------------------------------------------
// Relation GCN + fused attention pool -> sgbuf rows 4,5 (vrel eliminated)
// ---------------------------------------------------------------------------
__global__ __launch_bounds__(128)
void gcnrel_sg_kernel(const float* __restrict__ rel_emb,
                      const float* __restrict__ rel_ctx,
                      const float* __restrict__ Wr,
                      RelPtrs rp,
                      const float* __restrict__ v_rel,
                      float* __restrict__ sgbuf)
{
    __shared__ float sH[M1_][DIM_];
    __shared__ float sAH[M1_][DIM_];
    __shared__ float sA[M1_ * M1_];
    __shared__ float sred[2][M1_];
    const int b = blockIdx.x;
    const int cse = blockIdx.y;
    const int e = threadIdx.x;
    const int* adj2 = rp.adj2[cse];

    const float o = rel_emb[(size_t)rp.center[cse][b] * DIM_ + e];
    sH[0][e] = o;
    #pragma unroll
    for (int j = 1; j < M1_; ++j) {
        const int a0 = adj2[((b * M_) + (j - 1)) * 2 + 0];
        const int a1 = adj2[((b * M_) + (j - 1)) * 2 + 1];
        sH[j][e] = rel_ctx[(size_t)a0 * DIM_ + e] + rel_ctx[(size_t)a1 * DIM_ + e];
    }
    if (e < M1_ * M1_) sA[e] = rp.A[cse][b * (M1_ * M1_) + e];
    __syncthreads();

    #pragma unroll
    for (int i = 0; i < M1_; ++i) {
        float s = 0.f;
        #pragma unroll
        for (int jj = 0; jj < M1_; ++jj) s += sA[i * M1_ + jj] * sH[jj][e];
        sAH[i][e] = s;
    }
    __syncthreads();

    float vm[M1_];
    #pragma unroll
    for (int i = 0; i < M1_; ++i) vm[i] = 0.f;
    for (int d = 0; d < DIM_; ++d) {
        const float w = Wr[d * DIM_ + e];
        #pragma unroll
        for (int i = 0; i < M1_; ++i) vm[i] += sAH[i][d] * w;
    }
    #pragma unroll
    for (int i = 0; i < M1_; ++i) vm[i] = fmaxf(vm[i], 0.f);

    const float sg = attn_pool(vm, o, v_rel[e], sred, e);
    sgbuf[((size_t)(4 + cse) * B_ + b) * DIM_ + e] = sg;
}

// ---------------------------------------------------------------------------
// Entity subgraph pool: grid (B, 4). FAST: gather fp16 partials; else read vent.
// ---------------------------------------------------------------------------
template <bool FAST>
__global__ __launch_bounds__(128)
void sg_ent_kernel(GatherPtrs gp,
                   const float* __restrict__ ent_emb,
                   const _Float16* __restrict__ partial,
                   const float* __restrict__ vent,
                   const float* __restrict__ v_ent,
                   float* __restrict__ sgbuf)
{
    __shared__ int sRt[M1_ * M1_];
    __shared__ float sred[2][M1_];
    const int b = blockIdx.x, c = blockIdx.y, e = threadIdx.x;
    const int n = gp.nn[c][b];
    if (FAST && e < M1_ * M1_) sRt[e] = gp.Rt[c][b * (M1_ * M1_) + e];
    __syncthreads();

    const float o = ent_emb[(size_t)gp.center[c][b] * DIM_ + e];
    float vm[M1_];
    if (FAST) {
        #pragma unroll
        for (int j = 0; j < M1_; ++j) {
            float s = 0.f;
            if (j <= n) {
                const int base = (c * B_ + b) * (M1_ * M1_) + j * M1_;
                for (int k = 0; k <= n; ++k) {
                    const int r = sRt[j * M1_ + k];
                    if (r < NW_) s += (float)partial[(size_t)(base + k) * DIM_ + e];
                }
                s = fmaxf(s, 0.f);
            }
            vm[j] = s;
        }
    } else {
        const float* vmat = vent + ((size_t)(c * B_ + b)) * M1_ * DIM_;
        #pragma unroll
        for (int j = 0; j < M1_; ++j)
            vm[j] = (j <= n) ? fmaxf(vmat[j * DIM_ + e], 0.f) : 0.f;
    }

    const float sg = attn_pool(vm, o, v_ent[e], sred, e);
    sgbuf[((size_t)c * B_ + b) * DIM_ + e] = sg;
}

// ---------------------------------------------------------------------------
// Score: gating + two L2 norms. One block per b.
// ---------------------------------------------------------------------------
__global__ __launch_bounds__(128)
void score_kernel(GatherPtrs gp,
                  const float* __restrict__ ent_emb,
                  const float* __restrict__ rel_emb,
                  const int* __restrict__ pos_r, const int* __restrict__ neg_r,
                  const float* __restrict__ gate_e, const float* __restrict__ gate_r,
                  const float* __restrict__ sgbuf,
                  float* __restrict__ out)
{
    __shared__ float sred[2][2];
    const int b = blockIdx.x, e = threadIdx.x;

    float cvec[4], osg[4];
    #pragma unroll
    for (int c = 0; c < 4; ++c) {
        cvec[c] = ent_emb[(size_t)gp.center[c][b] * DIM_ + e];
        osg[c] = sgbuf[((size_t)c * B_ + b) * DIM_ + e];
    }
    const float rvec0 = rel_emb[(size_t)pos_r[b] * DIM_ + e];
    const float rvec1 = rel_emb[(size_t)neg_r[b] * DIM_ + e];
    const float rsg0 = sgbuf[((size_t)4 * B_ + b) * DIM_ + e];
    const float rsg1 = sgbuf[((size_t)5 * B_ + b) * DIM_ + e];

    const float ge = 1.f / (1.f + expf(-gate_e[e]));
    const float gr = 1.f / (1.f + expf(-gate_r[e]));
    const float ph_o = ge * cvec[0] + (1.f - ge) * osg[0];
    const float pt_o = ge * cvec[1] + (1.f - ge) * osg[1];
    const float nh_o = ge * cvec[2] + (1.f - ge) * osg[2];
    const float nt_o = ge * cvec[3] + (1.f - ge) * osg[3];
    const float pr_o = gr * rvec0 + (1.f - gr) * rsg0;
    const float nr_o = gr * rvec1 + (1.f - gr) * rsg1;

    const float pv = ph_o + pr_o - pt_o;
    const float nv = nh_o + nr_o - nt_o;
    float p[2] = { pv * pv, nv * nv };
    float sc[2];
    block_reduce_bcast<2>(p, sred, e, sc);
    if (e == 0) { out[b] = sqrtf(sc[0]); out[B_ + b] = sqrtf(sc[1]); }
}

extern "C" void kernel_launch(void* const* d_in, const int* in_sizes, int n_in,
                              void* d_out, int out_size, void* d_ws, size_t ws_size,
                              hipStream_t stream)
{
    const float* entity_emb   = (const float*)d_in[0];
    const float* relation_emb = (const float*)d_in[1];
    const float* entity_ctx   = (const float*)d_in[2];
    const float* relation_ctx = (const float*)d_in[3];
    const float* egw          = (const float*)d_in[4];
    const float* rgw          = (const float*)d_in[5];
    const float* gate_e       = (const float*)d_in[6];
    const float* gate_r       = (const float*)d_in[7];
    const float* v_ent        = (const float*)d_in[8];
    const float* v_rel        = (const float*)d_in[9];
    const int* pos_h = (const int*)d_in[10];
    const int* pos_r = (const int*)d_in[11];
    const int* pos_t = (const int*)d_in[12];
    const int* neg_h = (const int*)d_in[13];
    const int* neg_r = (const int*)d_in[14];
    const int* neg_t = (const int*)d_in[15];
    const int* ph_adj = (const int*)d_in[16];
    const int* pt_adj = (const int*)d_in[17];
    const int* nh_adj = (const int*)d_in[18];
    const int* nt_adj = (const int*)d_in[19];
    const int* pr_adj = (const int*)d_in[20];
    const int* nr_adj = (const int*)d_in[21];
    const int* ph_R = (const int*)d_in[22];
    const int* pt_R = (const int*)d_in[23];
    const int* nh_R = (const int*)d_in[24];
    const int* nt_R = (const int*)d_in[25];
    const int* ph_nn = (const int*)d_in[26];
    const int* pt_nn = (const int*)d_in[27];
    const int* nh_nn = (const int*)d_in[28];
    const int* nt_nn = (const int*)d_in[29];
    const float* ph_D = (const float*)d_in[30];
    const float* pt_D = (const float*)d_in[31];
    const float* nh_D = (const float*)d_in[32];
    const float* nt_D = (const float*)d_in[33];
    const float* pr_A = (const float*)d_in[34];
    const float* nr_A = (const float*)d_in[35];

    GatherPtrs gp;
    gp.center[0] = pos_h; gp.center[1] = pos_t; gp.center[2] = neg_h; gp.center[3] = neg_t;
    gp.adj[0] = ph_adj; gp.adj[1] = pt_adj; gp.adj[2] = nh_adj; gp.adj[3] = nt_adj;
    gp.nn[0] = ph_nn; gp.nn[1] = pt_nn; gp.nn[2] = nh_nn; gp.nn[3] = nt_nn;
    gp.Rt[0] = ph_R; gp.Rt[1] = pt_R; gp.Rt[2] = nh_R; gp.Rt[3] = nt_R;
    gp.Dm[0] = ph_D; gp.Dm[1] = pt_D; gp.Dm[2] = nh_D; gp.Dm[3] = nt_D;

    RelPtrs rp;
    rp.center[0] = pos_r; rp.center[1] = neg_r;
    rp.adj2[0] = pr_adj; rp.adj2[1] = nr_adj;
    rp.A[0] = pr_A; rp.A[1] = nr_A;

    char* wsb = (char*)d_ws;
    const size_t partialBytes = (size_t)NQUAD_ * DIM_ * 2;          // 126,877,696
    const size_t itemsBytes   = (size_t)NQUAD_ * 4;                 //   1,982,464
    const size_t sgBytes      = (size_t)6 * B_ * DIM_ * 4;          //   3,145,728
    const size_t fastNeed = partialBytes + itemsBytes + 4096 + sgBytes;
    const bool fast = (ws_size >= fastNeed);

    if (fast) {
        _Float16* partial = (_Float16*)wsb;
        int* items  = (int*)(wsb + partialBytes);
        int* meta   = (int*)(wsb + partialBytes + itemsBytes);
        float* sgbuf = (float*)(wsb + partialBytes + itemsBytes + 4096);
        int* hist    = meta;
        int* itemOff = meta + 256;
        int* bstart  = meta + 512;
        int* cursor  = meta + 768;

        hipMemsetAsync(meta, 0, 4096, stream);
        hist_kernel<<<dim3(121), dim3(1024), 0, stream>>>(gp, hist);
        scan_kernel<<<dim3(1), dim3(256), 0, stream>>>(hist, itemOff, bstart);
        scatter_kernel<<<dim3(121), dim3(1024), 0, stream>>>(gp, itemOff, cursor, items);
        rgcn_gemm_fast<<<dim3(MAXBLK_), dim3(256), 0, stream>>>(
            gp, entity_emb, entity_ctx, egw, items, itemOff, bstart, partial);
        gcnrel_sg_kernel<<<dim3(B_, 2), dim3(128), 0, stream>>>(
            relation_emb, relation_ctx, rgw, rp, v_rel, sgbuf);
        sg_ent_kernel<true><<<dim3(B_, 4), dim3(128), 0, stream>>>(
            gp, entity_emb, partial, nullptr, v_ent, sgbuf);
        score_kernel<<<dim3(B_), dim3(128), 0, stream>>>(
            gp, entity_emb, relation_emb, pos_r, neg_r, gate_e, gate_r, sgbuf, (float*)d_out);
    } else {
        // fallback: atomic accumulation into vent
        float* vent = (float*)wsb;
        const size_t ventBytes = (size_t)4 * B_ * M1_ * DIM_ * 4;   // 23,068,672
        float* sgbuf = (float*)(wsb + ventBytes);
        int* items   = (int*)(wsb + ventBytes + sgBytes);
        int* meta    = (int*)(wsb + ventBytes + sgBytes + itemsBytes);
        int* hist    = meta;
        int* itemOff = meta + 256;
        int* bstart  = meta + 512;
        int* cursor  = meta + 768;

        hipMemsetAsync(vent, 0, ventBytes, stream);
        hipMemsetAsync(meta, 0, 4096, stream);
        hist_kernel<<<dim3(121), dim3(1024), 0, stream>>>(gp, hist);
        scan_kernel<<<dim3(1), dim3(256), 0, stream>>>(hist, itemOff, bstart);
        scatter_kernel<<<dim3(121), dim3(1024), 0, stream>>>(gp, itemOff, cursor, items);
        rgcn_gemm_atomic<<<dim3(MAXBLK_), dim3(256), 0, stream>>>(
            gp, entity_emb, entity_ctx, egw, items, itemOff, bstart, vent);
        gcnrel_sg_kernel<<<dim3(B_, 2), dim3(128), 0, stream>>>(
            relation_emb, relation_ctx, rgw, rp, v_rel, sgbuf);
        sg_ent_kernel<false><<<dim3(B_, 4), dim3(128), 0, stream>>>(
            gp, entity_emb, nullptr, vent, v_ent, sgbuf);
        score_kernel<<<dim3(B_), dim3(128), 0, stream>>>(
            gp, entity_emb, relation_emb, pos_r, neg_r, gate_e, gate_r, sgbuf, (float*)d_out);
    }
}

// Round 5
// 163.695 us; speedup vs baseline: 6.3368x; 1.1767x over previous
//
#include <hip/hip_runtime.h>
#include <math.h>

#define B_   1024
#define M_   10
#define M1_  11
#define DIM_ 128
#define NW_  201                    // real weight rows; r >= 201 -> zero matrix
#define NQUAD_ (4*B_*M1_*M1_)       // 495616 (case,b,j,k) quadruples
#define IPB_  64                    // items per MFMA GEMM block
#define MAXBLK64_ (NW_ + NQUAD_/IPB_)
#define IPB32_ 32                   // fallback path
#define MAXBLK32_ (NW_ + NQUAD_/IPB32_)

typedef __attribute__((ext_vector_type(8))) short bf16x8;
typedef __attribute__((ext_vector_type(4))) float f32x4;

struct GatherPtrs {
    const int* center[4];
    const int* adj[4];
    const int* nn[4];
    const int* Rt[4];
    const float* Dm[4];
};

struct RelPtrs {
    const int* center[2];
    const int* adj2[2];
    const float* A[2];
};

__device__ __forceinline__ unsigned short f2bf(float f) {
    union { float f; unsigned u; } v; v.f = f;
    const unsigned r = v.u + 0x7FFFu + ((v.u >> 16) & 1u);   // RNE
    return (unsigned short)(r >> 16);
}

// ---------------------------------------------------------------------------
// Batched cross-wave reduction: sum p[N] over 128 threads, result broadcast.
// ---------------------------------------------------------------------------
template <int N>
__device__ __forceinline__ void block_reduce_bcast(float (&p)[N], float (*sred)[N],
                                                   int e, float (&sc)[N])
{
    #pragma unroll
    for (int off = 32; off; off >>= 1)
        #pragma unroll
        for (int i = 0; i < N; ++i) p[i] += __shfl_xor(p[i], off, 64);
    if ((e & 63) == 0) {
        #pragma unroll
        for (int i = 0; i < N; ++i) sred[e >> 6][i] = p[i];
    }
    __syncthreads();
    #pragma unroll
    for (int i = 0; i < N; ++i) sc[i] = sred[0][i] + sred[1][i];
}

__device__ __forceinline__ float attn_pool(const float (&vm)[M1_], float o, float ve,
                                           float (*sred)[M1_], int e)
{
    float p[M1_];
    #pragma unroll
    for (int j = 0; j < M1_; ++j) p[j] = fmaxf(vm[j] * o, 0.f) * ve;
    float sc[M1_];
    block_reduce_bcast<M1_>(p, sred, e, sc);
    float mx = sc[0];
    #pragma unroll
    for (int j = 1; j < M1_; ++j) mx = fmaxf(mx, sc[j]);
    float s = 0.f, ex[M1_];
    #pragma unroll
    for (int j = 0; j < M1_; ++j) { ex[j] = expf(sc[j] - mx); s += ex[j]; }
    const float inv = 1.f / s;
    float sg = 0.f;
    #pragma unroll
    for (int j = 0; j < M1_; ++j) sg += ex[j] * inv * vm[j];
    return sg;
}

// ---------------------------------------------------------------------------
// Weight prep: WT[t][e][d] = bf16(W[t][d][e]). One block per t.
// ---------------------------------------------------------------------------
__global__ __launch_bounds__(256)
void wconv_kernel(const float* __restrict__ W, unsigned short* __restrict__ WT)
{
    __shared__ float tile[32][33];
    const int t = blockIdx.x;
    const float* Ws = W + (size_t)t * DIM_ * DIM_;
    unsigned short* Wd = WT + (size_t)t * DIM_ * DIM_;
    const int tx = threadIdx.x & 31, ty = threadIdx.x >> 5;
    for (int bd = 0; bd < DIM_; bd += 32)
        for (int be = 0; be < DIM_; be += 32) {
            __syncthreads();
            #pragma unroll
            for (int r = ty; r < 32; r += 8)
                tile[r][tx] = Ws[(bd + r) * DIM_ + be + tx];
            __syncthreads();
            #pragma unroll
            for (int r = ty; r < 32; r += 8)
                Wd[(be + r) * DIM_ + bd + tx] = f2bf(tile[tx][r]);
        }
}

// ---------------------------------------------------------------------------
// Pass 1: histogram via LDS
// ---------------------------------------------------------------------------
__global__ __launch_bounds__(1024)
void hist_kernel(GatherPtrs gp, int* __restrict__ hist)
{
    __shared__ int lh[NW_];
    const int tid = threadIdx.x;
    if (tid < NW_) lh[tid] = 0;
    __syncthreads();
    #pragma unroll
    for (int s = 0; s < 4; ++s) {
        const int idx = blockIdx.x * 4096 + s * 1024 + tid;
        const int c = idx / (B_ * M1_ * M1_);
        const int rem = idx % (B_ * M1_ * M1_);
        const int b = rem / (M1_ * M1_);
        const int jk = rem % (M1_ * M1_);
        const int j = jk / M1_, k = jk % M1_;
        const int n = gp.nn[c][b];
        if (j <= n && k <= n) {
            const int r = gp.Rt[c][rem];
            if (r < NW_) atomicAdd(&lh[r], 1);
        }
    }
    __syncthreads();
    if (tid < NW_ && lh[tid]) atomicAdd(&hist[tid], lh[tid]);
}

// ---------------------------------------------------------------------------
// Pass 2: exclusive prefix sums — single block (both IPB variants)
// ---------------------------------------------------------------------------
template <int IPB>
__global__ __launch_bounds__(256)
void scan_kernel(const int* __restrict__ hist, int* __restrict__ itemOff,
                 int* __restrict__ bstart)
{
    __shared__ int h[NW_];
    __shared__ int io[NW_ + 1];
    __shared__ int bs[NW_ + 1];
    const int t = threadIdx.x;
    if (t < NW_) h[t] = hist[t];
    __syncthreads();
    if (t == 0) {
        int accI = 0, accB = 0;
        for (int i = 0; i < NW_; ++i) {
            io[i] = accI; bs[i] = accB;
            accI += h[i]; accB += (h[i] + IPB - 1) / IPB;
        }
        io[NW_] = accI; bs[NW_] = accB;
    }
    __syncthreads();
    if (t <= NW_) { itemOff[t] = io[t]; bstart[t] = bs[t]; }
}

// ---------------------------------------------------------------------------
// Pass 3: scatter with LDS ranking
// ---------------------------------------------------------------------------
__global__ __launch_bounds__(1024)
void scatter_kernel(GatherPtrs gp, const int* __restrict__ itemOff,
                    int* __restrict__ cursor, int* __restrict__ items)
{
    __shared__ int lh[NW_];
    __shared__ int lbase[NW_];
    const int tid = threadIdx.x;
    if (tid < NW_) lh[tid] = 0;
    __syncthreads();
    int rr[4], rk[4], pk[4];
    #pragma unroll
    for (int s = 0; s < 4; ++s) {
        const int idx = blockIdx.x * 4096 + s * 1024 + tid;
        const int c = idx / (B_ * M1_ * M1_);
        const int rem = idx % (B_ * M1_ * M1_);
        const int b = rem / (M1_ * M1_);
        const int jk = rem % (M1_ * M1_);
        const int j = jk / M1_, k = jk % M1_;
        const int n = gp.nn[c][b];
        rr[s] = -1;
        if (j <= n && k <= n) {
            const int r = gp.Rt[c][rem];
            if (r < NW_) {
                rr[s] = r;
                rk[s] = atomicAdd(&lh[r], 1);
                pk[s] = (c << 18) | (b << 8) | (j << 4) | k;
            }
        }
    }
    __syncthreads();
    if (tid < NW_) lbase[tid] = lh[tid] ? atomicAdd(&cursor[tid], lh[tid]) : 0;
    __syncthreads();
    #pragma unroll
    for (int s = 0; s < 4; ++s)
        if (rr[s] >= 0) items[itemOff[rr[s]] + lbase[rr[s]] + rk[s]] = pk[s];
}

// ---------------------------------------------------------------------------
// MFMA grouped GEMM (fast path). One block per (t, chunk of 64 items).
// C[64 x 128] = Hd[64 x 128] @ W[t][128 x 128], bf16 in / f32 acc.
// LDS rows are XOR-swizzled (byte o ^= (row&7)<<4) so 16-lane stride-256B
// fragment reads are bank-conflict-free.
// ---------------------------------------------------------------------------
__global__ __launch_bounds__(256)
void rgcn_gemm_mfma(GatherPtrs gp,
                    const float* __restrict__ ent_emb,
                    const float* __restrict__ ent_ctx,
                    const unsigned short* __restrict__ WT,   // [t][e][d] bf16
                    const int* __restrict__ items,
                    const int* __restrict__ itemOff,
                    const int* __restrict__ bstart,
                    _Float16* __restrict__ partial)
{
    __shared__ unsigned short sW[DIM_ * DIM_];   // 32 KB, [e][d] swizzled
    __shared__ unsigned short sH[IPB_ * DIM_];   // 16 KB, [item][d] swizzled, D-scaled
    __shared__ int sQ[IPB_];

    const int bid = blockIdx.x;
    if (bid >= bstart[NW_]) return;
    int lo = 0, hi = NW_;
    while (lo + 1 < hi) { const int mid = (lo + hi) >> 1; if (bstart[mid] <= bid) lo = mid; else hi = mid; }
    const int t = lo;
    const int istart = itemOff[t] + (bid - bstart[t]) * IPB_;
    const int nItems = min(IPB_, itemOff[t + 1] - istart);
    const int tid = threadIdx.x;

    // stage W[t] (32 KB): linear global read -> swizzled LDS write
    {
        const uint4* src = (const uint4*)(WT + (size_t)t * DIM_ * DIM_);
        #pragma unroll
        for (int i = 0; i < 8; ++i) {
            const int m = i * 256 + tid;               // 16B chunk id
            const int row = m >> 4;                     // 16 chunks per 256B row
            const int o = (m & 15) * 16;
            const int so = row * 256 + (o ^ ((row & 7) << 4));
            *reinterpret_cast<uint4*>(reinterpret_cast<char*>(sW) + so) = src[m];
        }
    }
    // stage H rows (D-scaled, bf16): 64 items x 16 chunks
    for (int m = tid; m < IPB_ * 16; m += 256) {
        const int it = m >> 4, ch = m & 15;
        unsigned short h[8];
        if (it < nItems) {
            const int p = items[istart + it];
            const int c = p >> 18, b = (p >> 8) & 1023, j = (p >> 4) & 15, k = p & 15;
            if (ch == 0) sQ[it] = ((c * B_ + b) * M1_ + j) * M1_ + k;
            const float* srow = (j == 0)
                ? ent_emb + (size_t)gp.center[c][b] * DIM_
                : ent_ctx + (size_t)gp.adj[c][b * M_ + (j - 1)] * DIM_;
            const float d = gp.Dm[c][(b * M1_ + j) * M1_ + k];
            const float4* s4 = (const float4*)srow + ch * 2;
            const float4 v0 = s4[0], v1 = s4[1];
            h[0] = f2bf(v0.x * d); h[1] = f2bf(v0.y * d);
            h[2] = f2bf(v0.z * d); h[3] = f2bf(v0.w * d);
            h[4] = f2bf(v1.x * d); h[5] = f2bf(v1.y * d);
            h[6] = f2bf(v1.z * d); h[7] = f2bf(v1.w * d);
        } else {
            if (ch == 0) sQ[it] = -1;
            #pragma unroll
            for (int i = 0; i < 8; ++i) h[i] = 0;
        }
        uint4 pkd;
        pkd.x = (unsigned)h[0] | ((unsigned)h[1] << 16);
        pkd.y = (unsigned)h[2] | ((unsigned)h[3] << 16);
        pkd.z = (unsigned)h[4] | ((unsigned)h[5] << 16);
        pkd.w = (unsigned)h[6] | ((unsigned)h[7] << 16);
        const int o = ch * 16;
        const int so = it * 256 + (o ^ ((it & 7) << 4));
        *reinterpret_cast<uint4*>(reinterpret_cast<char*>(sH) + so) = pkd;
    }
    __syncthreads();

    // 4 waves; wave w owns n-tiles {2w, 2w+1}, all 4 m-tiles.
    const int w = tid >> 6, l = tid & 63;
    const int lr = l & 15, lk = l >> 4;
    const f32x4 z = {0.f, 0.f, 0.f, 0.f};
    f32x4 acc[4][2];
    #pragma unroll
    for (int mi = 0; mi < 4; ++mi) { acc[mi][0] = z; acc[mi][1] = z; }

    #pragma unroll
    for (int kb = 0; kb < 4; ++kb) {
        const int o = kb * 64 + lk * 16;               // byte offset of 8 bf16 k's
        bf16x8 af[4], bfr[2];
        #pragma unroll
        for (int mi = 0; mi < 4; ++mi) {
            const int row = mi * 16 + lr;
            af[mi] = *reinterpret_cast<const bf16x8*>(
                reinterpret_cast<const char*>(sH) + row * 256 + (o ^ ((row & 7) << 4)));
        }
        #pragma unroll
        for (int ni = 0; ni < 2; ++ni) {
            const int row = (2 * w + ni) * 16 + lr;
            bfr[ni] = *reinterpret_cast<const bf16x8*>(
                reinterpret_cast<const char*>(sW) + row * 256 + (o ^ ((row & 7) << 4)));
        }
        #pragma unroll
        for (int mi = 0; mi < 4; ++mi)
            #pragma unroll
            for (int ni = 0; ni < 2; ++ni)
                acc[mi][ni] = __builtin_amdgcn_mfma_f32_16x16x32_bf16(
                    af[mi], bfr[ni], acc[mi][ni], 0, 0, 0);
    }

    // epilogue: C row = m (item), col = n. row=(l>>4)*4+reg, col=l&15 per tile.
    #pragma unroll
    for (int mi = 0; mi < 4; ++mi) {
        #pragma unroll
        for (int j = 0; j < 4; ++j) {
            const int it = mi * 16 + lk * 4 + j;
            const int q = sQ[it];
            if (q >= 0) {
                #pragma unroll
                for (int ni = 0; ni < 2; ++ni) {
                    const int col = (2 * w + ni) * 16 + lr;
                    partial[(size_t)q * DIM_ + col] = (_Float16)acc[mi][ni][j];
                }
            }
        }
    }
}

// ---------------------------------------------------------------------------
// Fallback grouped GEMM (f32 VALU + atomics), round-2 proven.
// ---------------------------------------------------------------------------
__global__ __launch_bounds__(256, 1)
void rgcn_gemm_atomic(GatherPtrs gp,
                      const float* __restrict__ ent_emb,
                      const float* __restrict__ ent_ctx,
                      const float* __restrict__ W,
                      const int* __restrict__ items,
                      const int* __restrict__ itemOff,
                      const int* __restrict__ bstart,
                      float* __restrict__ vent)
{
    __shared__ float4 sWv[DIM_ * DIM_ / 4];
    __shared__ float4 sHv[IPB32_ * DIM_ / 4];
    const int bid = blockIdx.x;
    if (bid >= bstart[NW_]) return;
    int lo = 0, hi = NW_;
    while (lo + 1 < hi) { const int mid = (lo + hi) >> 1; if (bstart[mid] <= bid) lo = mid; else hi = mid; }
    const int t = lo;
    const int istart = itemOff[t] + (bid - bstart[t]) * IPB32_;
    const int nItems = min(IPB32_, itemOff[t + 1] - istart);
    const int tid = threadIdx.x;

    const float4* Wg = (const float4*)(W + (size_t)t * DIM_ * DIM_);
    #pragma unroll
    for (int i = 0; i < 16; ++i) sWv[i * 256 + tid] = Wg[i * 256 + tid];
    {
        const int it = tid >> 3, part = tid & 7;
        float4* dst = sHv + it * (DIM_ / 4);
        if (it < nItems) {
            const int p = items[istart + it];
            const int c = p >> 18, b = (p >> 8) & 1023, j = (p >> 4) & 15, k = p & 15;
            const float* src = (j == 0)
                ? ent_emb + (size_t)gp.center[c][b] * DIM_
                : ent_ctx + (size_t)gp.adj[c][b * M_ + (j - 1)] * DIM_;
            const float d = gp.Dm[c][(b * M1_ + j) * M1_ + k];
            const float4* s4 = (const float4*)src;
            #pragma unroll
            for (int s = 0; s < 4; ++s) {
                float4 v = s4[part * 4 + s];
                v.x *= d; v.y *= d; v.z *= d; v.w *= d;
                dst[part * 4 + s] = v;
            }
        } else {
            const float4 zz = {0.f, 0.f, 0.f, 0.f};
            #pragma unroll
            for (int s = 0; s < 4; ++s) dst[part * 4 + s] = zz;
        }
    }
    __syncthreads();

    const int q = tid & 31, g = tid >> 5;
    float acc[4][4] = {};
    #pragma unroll 2
    for (int d0 = 0; d0 < DIM_; d0 += 4) {
        const float4 w0 = sWv[(d0 + 0) * 32 + q];
        const float4 w1 = sWv[(d0 + 1) * 32 + q];
        const float4 w2 = sWv[(d0 + 2) * 32 + q];
        const float4 w3 = sWv[(d0 + 3) * 32 + q];
        #pragma unroll
        for (int m = 0; m < 4; ++m) {
            const float4 h = sHv[(4 * g + m) * 32 + (d0 >> 2)];
            acc[m][0] += h.x * w0.x + h.y * w1.x + h.z * w2.x + h.w * w3.x;
            acc[m][1] += h.x * w0.y + h.y * w1.y + h.z * w2.y + h.w * w3.y;
            acc[m][2] += h.x * w0.z + h.y * w1.z + h.z * w2.z + h.w * w3.z;
            acc[m][3] += h.x * w0.w + h.y * w1.w + h.z * w2.w + h.w * w3.w;
        }
    }
    #pragma unroll
    for (int m = 0; m < 4; ++m) {
        const int it = 4 * g + m;
        if (it < nItems) {
            const int p = items[istart + it];
            const int c = p >> 18, b = (p >> 8) & 1023, j = (p >> 4) & 15;
            float* dstp = vent + (((size_t)(c * B_ + b)) * M1_ + j) * DIM_ + 4 * q;
            unsafeAtomicAdd(dstp + 0, acc[m][0]);
            unsafeAtomicAdd(dstp + 1, acc[m][1]);
            unsafeAtomicAdd(dstp + 2, acc[m][2]);
            unsafeAtomicAdd(dstp + 3, acc[m][3]);
        }
    }
}

// ---------------------------------------------------------------------------
// Relation GCN + fused attention pool -> sgbuf rows 4,5
// ---------------------------------------------------------------------------
__global__ __launch_bounds__(128)
void gcnrel_sg_kernel(const float* __restrict__ rel_emb,
                      const float* __restrict__ rel_ctx,
                      const float* __restrict__ Wr,
                      RelPtrs rp,
                      const float* __restrict__ v_rel,
                      float* __restrict__ sgbuf)
{
    __shared__ float sH[M1_][DIM_];
    __shared__ float sAH[M1_][DIM_];
    __shared__ float sA[M1_ * M1_];
    __shared__ float sred[2][M1_];
    const int b = blockIdx.x;
    const int cse = blockIdx.y;
    const int e = threadIdx.x;
    const int* adj2 = rp.adj2[cse];

    const float o = rel_emb[(size_t)rp.center[cse][b] * DIM_ + e];
    sH[0][e] = o;
    #pragma unroll
    for (int j = 1; j < M1_; ++j) {
        const int a0 = adj2[((b * M_) + (j - 1)) * 2 + 0];
        const int a1 = adj2[((b * M_) + (j - 1)) * 2 + 1];
        sH[j][e] = rel_ctx[(size_t)a0 * DIM_ + e] + rel_ctx[(size_t)a1 * DIM_ + e];
    }
    if (e < M1_ * M1_) sA[e] = rp.A[cse][b * (M1_ * M1_) + e];
    __syncthreads();

    #pragma unroll
    for (int i = 0; i < M1_; ++i) {
        float s = 0.f;
        #pragma unroll
        for (int jj = 0; jj < M1_; ++jj) s += sA[i * M1_ + jj] * sH[jj][e];
        sAH[i][e] = s;
    }
    __syncthreads();

    float vm[M1_];
    #pragma unroll
    for (int i = 0; i < M1_; ++i) vm[i] = 0.f;
    for (int d = 0; d < DIM_; ++d) {
        const float wv = Wr[d * DIM_ + e];
        #pragma unroll
        for (int i = 0; i < M1_; ++i) vm[i] += sAH[i][d] * wv;
    }
    #pragma unroll
    for (int i = 0; i < M1_; ++i) vm[i] = fmaxf(vm[i], 0.f);

    const float sg = attn_pool(vm, o, v_rel[e], sred, e);
    sgbuf[((size_t)(4 + cse) * B_ + b) * DIM_ + e] = sg;
}

// ---------------------------------------------------------------------------
// Entity subgraph pool: grid (B, 4)
// ---------------------------------------------------------------------------
template <bool FAST>
__global__ __launch_bounds__(128)
void sg_ent_kernel(GatherPtrs gp,
                   const float* __restrict__ ent_emb,
                   const _Float16* __restrict__ partial,
                   const float* __restrict__ vent,
                   const float* __restrict__ v_ent,
                   float* __restrict__ sgbuf)
{
    __shared__ int sRt[M1_ * M1_];
    __shared__ float sred[2][M1_];
    const int b = blockIdx.x, c = blockIdx.y, e = threadIdx.x;
    const int n = gp.nn[c][b];
    if (FAST && e < M1_ * M1_) sRt[e] = gp.Rt[c][b * (M1_ * M1_) + e];
    __syncthreads();

    const float o = ent_emb[(size_t)gp.center[c][b] * DIM_ + e];
    float vm[M1_];
    if (FAST) {
        #pragma unroll
        for (int j = 0; j < M1_; ++j) {
            float s = 0.f;
            if (j <= n) {
                const int base = (c * B_ + b) * (M1_ * M1_) + j * M1_;
                for (int k = 0; k <= n; ++k) {
                    const int r = sRt[j * M1_ + k];
                    if (r < NW_) s += (float)partial[(size_t)(base + k) * DIM_ + e];
                }
                s = fmaxf(s, 0.f);
            }
            vm[j] = s;
        }
    } else {
        const float* vmat = vent + ((size_t)(c * B_ + b)) * M1_ * DIM_;
        #pragma unroll
        for (int j = 0; j < M1_; ++j)
            vm[j] = (j <= n) ? fmaxf(vmat[j * DIM_ + e], 0.f) : 0.f;
    }

    const float sg = attn_pool(vm, o, v_ent[e], sred, e);
    sgbuf[((size_t)c * B_ + b) * DIM_ + e] = sg;
}

// ---------------------------------------------------------------------------
// Score: gating + two L2 norms
// ---------------------------------------------------------------------------
__global__ __launch_bounds__(128)
void score_kernel(GatherPtrs gp,
                  const float* __restrict__ ent_emb,
                  const float* __restrict__ rel_emb,
                  const int* __restrict__ pos_r, const int* __restrict__ neg_r,
                  const float* __restrict__ gate_e, const float* __restrict__ gate_r,
                  const float* __restrict__ sgbuf,
                  float* __restrict__ out)
{
    __shared__ float sred[2][2];
    const int b = blockIdx.x, e = threadIdx.x;

    float cvec[4], osg[4];
    #pragma unroll
    for (int c = 0; c < 4; ++c) {
        cvec[c] = ent_emb[(size_t)gp.center[c][b] * DIM_ + e];
        osg[c] = sgbuf[((size_t)c * B_ + b) * DIM_ + e];
    }
    const float rvec0 = rel_emb[(size_t)pos_r[b] * DIM_ + e];
    const float rvec1 = rel_emb[(size_t)neg_r[b] * DIM_ + e];
    const float rsg0 = sgbuf[((size_t)4 * B_ + b) * DIM_ + e];
    const float rsg1 = sgbuf[((size_t)5 * B_ + b) * DIM_ + e];

    const float ge = 1.f / (1.f + expf(-gate_e[e]));
    const float gr = 1.f / (1.f + expf(-gate_r[e]));
    const float ph_o = ge * cvec[0] + (1.f - ge) * osg[0];
    const float pt_o = ge * cvec[1] + (1.f - ge) * osg[1];
    const float nh_o = ge * cvec[2] + (1.f - ge) * osg[2];
    const float nt_o = ge * cvec[3] + (1.f - ge) * osg[3];
    const float pr_o = gr * rvec0 + (1.f - gr) * rsg0;
    const float nr_o = gr * rvec1 + (1.f - gr) * rsg1;

    const float pv = ph_o + pr_o - pt_o;
    const float nv = nh_o + nr_o - nt_o;
    float p[2] = { pv * pv, nv * nv };
    float sc[2];
    block_reduce_bcast<2>(p, sred, e, sc);
    if (e == 0) { out[b] = sqrtf(sc[0]); out[B_ + b] = sqrtf(sc[1]); }
}

extern "C" void kernel_launch(void* const* d_in, const int* in_sizes, int n_in,
                              void* d_out, int out_size, void* d_ws, size_t ws_size,
                              hipStream_t stream)
{
    const float* entity_emb   = (const float*)d_in[0];
    const float* relation_emb = (const float*)d_in[1];
    const float* entity_ctx   = (const float*)d_in[2];
    const float* relation_ctx = (const float*)d_in[3];
    const float* egw          = (const float*)d_in[4];
    const float* rgw          = (const float*)d_in[5];
    const float* gate_e       = (const float*)d_in[6];
    const float* gate_r       = (const float*)d_in[7];
    const float* v_ent        = (const float*)d_in[8];
    const float* v_rel        = (const float*)d_in[9];
    const int* pos_h = (const int*)d_in[10];
    const int* pos_r = (const int*)d_in[11];
    const int* pos_t = (const int*)d_in[12];
    const int* neg_h = (const int*)d_in[13];
    const int* neg_r = (const int*)d_in[14];
    const int* neg_t = (const int*)d_in[15];
    const int* ph_adj = (const int*)d_in[16];
    const int* pt_adj = (const int*)d_in[17];
    const int* nh_adj = (const int*)d_in[18];
    const int* nt_adj = (const int*)d_in[19];
    const int* pr_adj = (const int*)d_in[20];
    const int* nr_adj = (const int*)d_in[21];
    const int* ph_R = (const int*)d_in[22];
    const int* pt_R = (const int*)d_in[23];
    const int* nh_R = (const int*)d_in[24];
    const int* nt_R = (const int*)d_in[25];
    const int* ph_nn = (const int*)d_in[26];
    const int* pt_nn = (const int*)d_in[27];
    const int* nh_nn = (const int*)d_in[28];
    const int* nt_nn = (const int*)d_in[29];
    const float* ph_D = (const float*)d_in[30];
    const float* pt_D = (const float*)d_in[31];
    const float* nh_D = (const float*)d_in[32];
    const float* nt_D = (const float*)d_in[33];
    const float* pr_A = (const float*)d_in[34];
    const float* nr_A = (const float*)d_in[35];

    GatherPtrs gp;
    gp.center[0] = pos_h; gp.center[1] = pos_t; gp.center[2] = neg_h; gp.center[3] = neg_t;
    gp.adj[0] = ph_adj; gp.adj[1] = pt_adj; gp.adj[2] = nh_adj; gp.adj[3] = nt_adj;
    gp.nn[0] = ph_nn; gp.nn[1] = pt_nn; gp.nn[2] = nh_nn; gp.nn[3] = nt_nn;
    gp.Rt[0] = ph_R; gp.Rt[1] = pt_R; gp.Rt[2] = nh_R; gp.Rt[3] = nt_R;
    gp.Dm[0] = ph_D; gp.Dm[1] = pt_D; gp.Dm[2] = nh_D; gp.Dm[3] = nt_D;

    RelPtrs rp;
    rp.center[0] = pos_r; rp.center[1] = neg_r;
    rp.adj2[0] = pr_adj; rp.adj2[1] = nr_adj;
    rp.A[0] = pr_A; rp.A[1] = nr_A;

    char* wsb = (char*)d_ws;
    const size_t partialBytes = (size_t)NQUAD_ * DIM_ * 2;          // 126,877,696
    const size_t itemsBytes   = (size_t)NQUAD_ * 4;                 //   1,982,464
    const size_t wtBytes      = (size_t)NW_ * DIM_ * DIM_ * 2;      //   6,586,368
    const size_t sgBytes      = (size_t)6 * B_ * DIM_ * 4;          //   3,145,728
    const size_t wsgBytes     = wtBytes > sgBytes ? wtBytes : sgBytes;
    const size_t fastNeed = partialBytes + itemsBytes + 4096 + wsgBytes; // ~135.5 MB
    const bool fast = (ws_size >= fastNeed);

    if (fast) {
        _Float16* partial = (_Float16*)wsb;
        int* items  = (int*)(wsb + partialBytes);
        int* meta   = (int*)(wsb + partialBytes + itemsBytes);
        // WT (prep->gemm) and sgbuf (gcnrel_sg/sg_ent->score) share this region:
        // WT is dead after rgcn_gemm_mfma completes; stream order guarantees safety.
        char* wsg   = wsb + partialBytes + itemsBytes + 4096;
        unsigned short* WT = (unsigned short*)wsg;
        float* sgbuf       = (float*)wsg;
        int* hist    = meta;
        int* itemOff = meta + 256;
        int* bstart  = meta + 512;
        int* cursor  = meta + 768;

        hipMemsetAsync(meta, 0, 4096, stream);
        wconv_kernel<<<dim3(NW_), dim3(256), 0, stream>>>(egw, WT);
        hist_kernel<<<dim3(121), dim3(1024), 0, stream>>>(gp, hist);
        scan_kernel<IPB_><<<dim3(1), dim3(256), 0, stream>>>(hist, itemOff, bstart);
        scatter_kernel<<<dim3(121), dim3(1024), 0, stream>>>(gp, itemOff, cursor, items);
        rgcn_gemm_mfma<<<dim3(MAXBLK64_), dim3(256), 0, stream>>>(
            gp, entity_emb, entity_ctx, WT, items, itemOff, bstart, partial);
        gcnrel_sg_kernel<<<dim3(B_, 2), dim3(128), 0, stream>>>(
            relation_emb, relation_ctx, rgw, rp, v_rel, sgbuf);
        sg_ent_kernel<true><<<dim3(B_, 4), dim3(128), 0, stream>>>(
            gp, entity_emb, partial, nullptr, v_ent, sgbuf);
        score_kernel<<<dim3(B_), dim3(128), 0, stream>>>(
            gp, entity_emb, relation_emb, pos_r, neg_r, gate_e, gate_r, sgbuf, (float*)d_out);
    } else {
        // fallback: atomic accumulation into vent (f32 VALU path)
        float* vent = (float*)wsb;
        const size_t ventBytes = (size_t)4 * B_ * M1_ * DIM_ * 4;   // 23,068,672
        float* sgbuf = (float*)(wsb + ventBytes);
        int* items   = (int*)(wsb + ventBytes + sgBytes);
        int* meta    = (int*)(wsb + ventBytes + sgBytes + itemsBytes);
        int* hist    = meta;
        int* itemOff = meta + 256;
        int* bstart  = meta + 512;
        int* cursor  = meta + 768;

        hipMemsetAsync(vent, 0, ventBytes, stream);
        hipMemsetAsync(meta, 0, 4096, stream);
        hist_kernel<<<dim3(121), dim3(1024), 0, stream>>>(gp, hist);
        scan_kernel<IPB32_><<<dim3(1), dim3(256), 0, stream>>>(hist, itemOff, bstart);
        scatter_kernel<<<dim3(121), dim3(1024), 0, stream>>>(gp, itemOff, cursor, items);
        rgcn_gemm_atomic<<<dim3(MAXBLK32_), dim3(256), 0, stream>>>(
            gp, entity_emb, entity_ctx, egw, items, itemOff, bstart, vent);
        gcnrel_sg_kernel<<<dim3(B_, 2), dim3(128), 0, stream>>>(
            relation_emb, relation_ctx, rgw, rp, v_rel, sgbuf);
        sg_ent_kernel<false><<<dim3(B_, 4), dim3(128), 0, stream>>>(
            gp, entity_emb, nullptr, vent, v_ent, sgbuf);
        score_kernel<<<dim3(B_), dim3(128), 0, stream>>>(
            gp, entity_emb, relation_emb, pos_r, neg_r, gate_e, gate_r, sgbuf, (float*)d_out);
    }
}